// Round 1
// baseline (402.933 us; speedup 1.0000x reference)
//
#include <hip/hip_runtime.h>

#define SEQ 4096
#define NBATCH 256

typedef float v2f __attribute__((ext_vector_type(2)));

__device__ __forceinline__ float sqf(float v) { return v * v; }
__device__ __forceinline__ float fexp2(float v) { return __builtin_amdgcn_exp2f(v); }
__device__ __forceinline__ float frcp(float v)  { return __builtin_amdgcn_rcpf(v); }

#define L2E 1.4426950408889634f

// order-preserving float<->uint key for atomicMax on floats
__device__ __forceinline__ unsigned fkey(float f) {
    const int b = __float_as_int(f);
    return (unsigned)(b ^ ((b >> 31) | 0x80000000));
}
__device__ __forceinline__ float fival(unsigned k) {
    const int b = (k & 0x80000000u) ? (int)(k ^ 0x80000000u) : (int)(~k);
    return __int_as_float(b);
}

// ---------------------------------------------------------------------------
// Kernel 0: fold the 24-wide input matvec into 12 inputs + bias, pre-scaled
// by the row's activation pre-scale (-log2e; -2log2e for g rows).
// Also zero-initializes the MMu atomic-max buffer (re-poisoned every call).
// ---------------------------------------------------------------------------
__global__ void wprep_kernel(
    const float* __restrict__ Wih_f, const float* __restrict__ bih_f,
    const float* __restrict__ bhh_f,
    const float* __restrict__ Wih_r, const float* __restrict__ bih_r,
    const float* __restrict__ bhh_r,
    float* __restrict__ Wp, unsigned* __restrict__ MMu)
{
    const int t = threadIdx.x;
    for (int i = t; i < NBATCH * 5; i += 256) MMu[i] = 0u;  // key 0 < any real
    if (t >= 80) return;
    const int d = t / 40, r = t % 40;
    const float* __restrict__ W  = (d ? Wih_r : Wih_f) + r * 24;
    const float* __restrict__ bi = d ? bih_r : bih_f;
    const float* __restrict__ bh = d ? bhh_r : bhh_f;
    const float sc = (r >= 20 && r < 30) ? (-2.f * L2E) : (-L2E);
    float o[13];
    o[0]  = W[0] + W[1] + W[2] + W[3];                // v4s
    o[1]  = W[4] + W[5] + W[6] + W[7];                // v5s
    o[2]  = W[4];                                     // v5p
    o[3]  = W[8] + W[9] + W[10] + W[11];              // v6s
    o[4]  = W[8] + W[9];                              // v6p
    o[5]  = W[12] + W[13] + W[14] + W[15];            // v7s
    o[6]  = W[12] + W[13] + W[14];                    // v7p
    o[7]  = W[16] + W[17] + W[18] + W[19];            // v8s+v8p
    o[8]  = W[20]; o[9] = W[21]; o[10] = W[22]; o[11] = W[23];   // x0..x3
    o[12] = bi[r] + bh[r];
    float* __restrict__ out = Wp + (d * 40 + r) * 16;
#pragma unroll
    for (int k = 0; k < 13; ++k) out[k] = o[k] * sc;
    out[13] = 0.f; out[14] = 0.f; out[15] = 0.f;
}

// ---------------------------------------------------------------------------
// Kernel 1a: per-batch conv max -> atomicMax on uint keys.
// ---------------------------------------------------------------------------
__global__ __launch_bounds__(256) void max_kernel(
    const float* __restrict__ x,
    const float* __restrict__ w4p, const float* __restrict__ w5p,
    const float* __restrict__ w6p, const float* __restrict__ w7p,
    const float* __restrict__ w8p,
    unsigned* __restrict__ MMu)
{
    const int b    = blockIdx.x >> 2;
    const int quar = blockIdx.x & 3;
    const int tid  = threadIdx.x;
    const float* __restrict__ xr = x + (size_t)b * (4 * SEQ);

    float W4[4], W5[5], W6[6], W7[7], W8[8];
#pragma unroll
    for (int k = 0; k < 4; ++k) W4[k] = w4p[k];
#pragma unroll
    for (int k = 0; k < 5; ++k) W5[k] = w5p[k];
#pragma unroll
    for (int k = 0; k < 6; ++k) W6[k] = w6p[k];
#pragma unroll
    for (int k = 0; k < 7; ++k) W7[k] = w7p[k];
#pragma unroll
    for (int k = 0; k < 8; ++k) W8[k] = w8p[k];

    float m4 = -3.4e38f, m5 = -3.4e38f, m6 = -3.4e38f, m7 = -3.4e38f, m8 = -3.4e38f;
    for (int i = quar * (SEQ / 4) + tid; i < (quar + 1) * (SEQ / 4); i += 256) {
        const float4 t0 = *reinterpret_cast<const float4*>(xr + 4 * i);
        const float xa0 = t0.x, xa1 = t0.y, xa2 = t0.z, xa3 = t0.w;
        const float c4 = xa0 * W4[0] + xa1 * W4[1] + xa2 * W4[2] + xa3 * W4[3];
        m4 = fmaxf(m4, c4);
        if (i < SEQ - 1) {
            const float4 t1 = *reinterpret_cast<const float4*>(xr + 4 * i + 4);
            const float xa4 = t1.x, xa5 = t1.y, xa6 = t1.z, xa7 = t1.w;
            const float c5 = xa0*W5[0]+xa1*W5[1]+xa2*W5[2]+xa3*W5[3]+xa4*W5[4];
            const float c6 = xa0*W6[0]+xa1*W6[1]+xa2*W6[2]+xa3*W6[3]+xa4*W6[4]+xa5*W6[5];
            const float c7 = xa0*W7[0]+xa1*W7[1]+xa2*W7[2]+xa3*W7[3]+xa4*W7[4]+xa5*W7[5]+xa6*W7[6];
            const float c8 = xa0*W8[0]+xa1*W8[1]+xa2*W8[2]+xa3*W8[3]+xa4*W8[4]+xa5*W8[5]+xa6*W8[6]+xa7*W8[7];
            m5 = fmaxf(m5, c5); m6 = fmaxf(m6, c6);
            m7 = fmaxf(m7, c7); m8 = fmaxf(m8, c8);
        }
    }
#pragma unroll
    for (int off = 32; off; off >>= 1) {
        m4 = fmaxf(m4, __shfl_down(m4, off));
        m5 = fmaxf(m5, __shfl_down(m5, off));
        m6 = fmaxf(m6, __shfl_down(m6, off));
        m7 = fmaxf(m7, __shfl_down(m7, off));
        m8 = fmaxf(m8, __shfl_down(m8, off));
    }
    __shared__ float wr[4][5];
    if ((tid & 63) == 0) {
        const int w = tid >> 6;
        wr[w][0] = m4; wr[w][1] = m5; wr[w][2] = m6; wr[w][3] = m7; wr[w][4] = m8;
    }
    __syncthreads();
    if (tid < 5) {
        const float m = fmaxf(fmaxf(wr[0][tid], wr[1][tid]),
                              fmaxf(wr[2][tid], wr[3][tid]));
        atomicMax(&MMu[b * 5 + tid], fkey(m));
    }
}

// ---------------------------------------------------------------------------
// Kernel 1b: winner-takes-all -> compressed 12-input rows.
// lin[b][s][16] = {v4s, v5s, v5p, v6s, v6p, v7s, v7p, v8s+v8p,
//                  x0, x1, x2, x3, xsum, 0,0,0}
// ---------------------------------------------------------------------------
__global__ __launch_bounds__(256) void scatter_kernel(
    const float* __restrict__ x,
    const float* __restrict__ w4p, const float* __restrict__ w5p,
    const float* __restrict__ w6p, const float* __restrict__ w7p,
    const float* __restrict__ w8p,
    const unsigned* __restrict__ MMu,
    float* __restrict__ lin)
{
    const int b    = blockIdx.x >> 2;
    const int quar = blockIdx.x & 3;
    const int tid  = threadIdx.x;
    const float* __restrict__ xr = x + (size_t)b * (4 * SEQ);

    float W4[4], W5[5], W6[6], W7[7], W8[8];
#pragma unroll
    for (int k = 0; k < 4; ++k) W4[k] = w4p[k];
#pragma unroll
    for (int k = 0; k < 5; ++k) W5[k] = w5p[k];
#pragma unroll
    for (int k = 0; k < 6; ++k) W6[k] = w6p[k];
#pragma unroll
    for (int k = 0; k < 7; ++k) W7[k] = w7p[k];
#pragma unroll
    for (int k = 0; k < 8; ++k) W8[k] = w8p[k];

    const float M4 = fival(MMu[b * 5 + 0]), M5 = fival(MMu[b * 5 + 1]),
                M6 = fival(MMu[b * 5 + 2]), M7 = fival(MMu[b * 5 + 3]),
                M8 = fival(MMu[b * 5 + 4]);

    for (int s = quar * (SEQ / 4) + tid; s < (quar + 1) * (SEQ / 4); s += 256) {
        float xw[12];
        if (s > 0) {
            const float4 t = *reinterpret_cast<const float4*>(xr + 4 * s - 4);
            xw[0] = t.x; xw[1] = t.y; xw[2] = t.z; xw[3] = t.w;
        } else { xw[0] = xw[1] = xw[2] = xw[3] = 0.f; }
        {
            const float4 t = *reinterpret_cast<const float4*>(xr + 4 * s);
            xw[4] = t.x; xw[5] = t.y; xw[6] = t.z; xw[7] = t.w;
        }
        if (s < SEQ - 1) {
            const float4 t = *reinterpret_cast<const float4*>(xr + 4 * s + 4);
            xw[8] = t.x; xw[9] = t.y; xw[10] = t.z; xw[11] = t.w;
        } else { xw[8] = xw[9] = xw[10] = xw[11] = 0.f; }

        float c4s = 0.f, c5s = 0.f, c6s = 0.f, c7s = 0.f, c8s = 0.f;
        float c5p = 0.f, c6p = 0.f, c7p = 0.f, c8p = 0.f;
#pragma unroll
        for (int t = 0; t < 4; ++t) c4s += xw[4 + t] * W4[t];
#pragma unroll
        for (int t = 0; t < 5; ++t) { c5s += xw[4 + t] * W5[t]; c5p += xw[t] * W5[t]; }
#pragma unroll
        for (int t = 0; t < 6; ++t) { c6s += xw[4 + t] * W6[t]; c6p += xw[t] * W6[t]; }
#pragma unroll
        for (int t = 0; t < 7; ++t) { c7s += xw[4 + t] * W7[t]; c7p += xw[t] * W7[t]; }
#pragma unroll
        for (int t = 0; t < 8; ++t) { c8s += xw[4 + t] * W8[t]; c8p += xw[t] * W8[t]; }

        const bool oks = (s < SEQ - 1);
        const bool okp = (s > 0);
        const float v4s = sqf(c4s + M4);
        const float v5s = oks ? sqf(c5s + M5) : 0.f;
        const float v6s = oks ? sqf(c6s + M6) : 0.f;
        const float v7s = oks ? sqf(c7s + M7) : 0.f;
        const float v8s = oks ? sqf(c8s + M8) : 0.f;
        const float v5p = okp ? sqf(c5p + M5) : 0.f;
        const float v6p = okp ? sqf(c6p + M6) : 0.f;
        const float v7p = okp ? sqf(c7p + M7) : 0.f;
        const float v8p = okp ? sqf(c8p + M8) : 0.f;

        const float xsum = (xw[4] + xw[5]) + (xw[6] + xw[7]);
        float4* op = reinterpret_cast<float4*>(lin + ((size_t)b * SEQ + s) * 16);
        op[0] = make_float4(v4s, v5s, v5p, v6s);
        op[1] = make_float4(v6p, v7s, v7p, v8s + v8p);
        op[2] = make_float4(xw[4], xw[5], xw[6], xw[7]);
        op[3] = make_float4(xsum, 0.f, 0.f, 0.f);
    }
}

// ---------------------------------------------------------------------------
// Kernel 2: K=16 segmented bidirectional LSTM, 4 spatial chains x 4 TEMPORAL
// segments per wave (r0 of this session: 2-way ILP left VALU 55% idle at
// 1 wave/SIMD; 4-way interleave doubles chain ILP at +33% warmup work).
// nseg=32 segments of 128 own steps + 128 warm steps. Grid unchanged:
// 8 q x 2 dir x 64 bgroups = 1024 blocks x 64 thr = 1 wave/SIMD.
// Chunk = 8 steps; producer half-split: lanes 0-31 fill seg-pair (A,B),
// lanes 32-63 fill (C,D) -- keeps the A/B v2f pk_fma packing intact.
// Transcendentals fused: sigmoid(i)*tanh(g) and sigmoid(o)*tanh(c) each
// computed with a single rcp of the product denominator (5 exp + 3 rcp per
// step, was 5+5). fminf(.,80) clamps are bit-exact unless tanh==+-1 in f32.
// All segments run 128 warm + 128 owned steps; seg0 resets (h,c)=0 after
// warm so its state at step 0 is exact (warm=128 validated prev session).
// ---------------------------------------------------------------------------
__global__ __launch_bounds__(64) void lstm_kernel(
    const float* __restrict__ lin,
    const float* __restrict__ Wp,
    const float* __restrict__ Whh_f,
    const float* __restrict__ Whh_r,
    float* __restrict__ P)
{
    const int bg   = blockIdx.x & 63;
    const int d    = (blockIdx.x >> 6) & 1;
    const int q    = blockIdx.x >> 7;          // 0..7 -> segments 4q..4q+3
    const int b0   = bg * 4;
    const int lane = threadIdx.x;

    const int nChunks = 32, warmChunks = 16;   // 8-step chunks: 128w + 128o

    __shared__ float gbuf[4][8 * 4 * 44];
    __shared__ float xbuf[4][32];
    __shared__ float wbuf[640];                // folded input weights, this dir

    {
        const float* __restrict__ src = Wp + d * 640;
#pragma unroll
        for (int qq = 0; qq < 10; ++qq) wbuf[lane + 64 * qq] = src[lane + 64 * qq];
    }
    asm volatile("s_waitcnt lgkmcnt(0)" ::: "memory");

    // ---- consumer setup: c = lane>>4 (chain), jr = lane&15 (unit) ----
    const int c   = lane >> 4;
    const int jr  = lane & 15;
    const int jc  = (jr < 10) ? jr : 0;
    const int gb4 = (lane & 48) << 2;          // group base byte idx for bpermute

    const float* __restrict__ Whh = d ? Whh_r : Whh_f;
    v2f wIF[10], wGO[10];
#pragma unroll
    for (int k = 0; k < 10; ++k) {
        wIF[k] = (v2f){Whh[jc * 10 + k]        * (-L2E),
                       Whh[(10 + jc) * 10 + k] * (-L2E)};
        wGO[k] = (v2f){Whh[(20 + jc) * 10 + k] * (-2.f * L2E),
                       Whh[(30 + jc) * 10 + k] * (-L2E)};
    }

    // ---- producer setup: half = seg-pair, cc = chain, r = step-in-chunk ----
    const int half = lane >> 5;                // 0: segs (4q,4q+1)  1: (4q+2,4q+3)
    const int cc   = lane & 3;
    const int r    = (lane >> 2) & 7;          // 0..7
    const int pair = 2 * half;
    const int s0A  = (4 * q + pair) * 128 - 128;   // may be negative for q=0
    const int s0B  = s0A + 128;
    const float* __restrict__ chbase = lin + (size_t)(b0 + cc) * SEQ * 16;

    auto rowp = [&](int s0, int cn) {
        int sp = s0 + cn * 8 + r;
        if (sp < 0) sp = 0;                    // q=0 warm region: clamped garbage,
                                               // discarded by the state reset
        const int pos = d ? (SEQ - 1 - sp) : sp;
        return reinterpret_cast<const float4*>(chbase + (size_t)pos * 16);
    };

    float4 pA[4], pB[4];
    {
        const float4* a = rowp(s0A, 0);
        pA[0] = a[0]; pA[1] = a[1]; pA[2] = a[2]; pA[3] = a[3];
        const float4* bq = rowp(s0B, 0);
        pB[0] = bq[0]; pB[1] = bq[1]; pB[2] = bq[2]; pB[3] = bq[3];
    }

    float cs[4]   = {0.f, 0.f, 0.f, 0.f};
    float hh[4]   = {0.f, 0.f, 0.f, 0.f};
    float accS[4] = {0.f, 0.f, 0.f, 0.f};

    // one recurrence step (consumer)
    auto step = [&](const float* gb, const float* xb, float& csv, float& hv,
                    float& aS, int i) {
        const float4 gp4 =
            *reinterpret_cast<const float4*>(&gb[(i * 4 + c) * 44 + jc * 4]);
        const float sx = xb[i * 4 + c];
        const int hb = __float_as_int(hv);
        float hj[10];
#pragma unroll
        for (int k = 0; k < 10; ++k)
            hj[k] = __int_as_float(__builtin_amdgcn_ds_bpermute(gb4 + 4 * k, hb));
        v2f eif0 = (v2f){gp4.x, gp4.y}, eif1 = (v2f){0.f, 0.f};
        v2f ego0 = (v2f){gp4.z, gp4.w}, ego1 = (v2f){0.f, 0.f};
#pragma unroll
        for (int k = 0; k < 10; k += 2) {
            const v2f h0 = (v2f){hj[k], hj[k]};
            const v2f h1 = (v2f){hj[k + 1], hj[k + 1]};
            eif0 += h0 * wIF[k]; eif1 += h1 * wIF[k + 1];
            ego0 += h0 * wGO[k]; ego1 += h1 * wGO[k + 1];
        }
        const v2f eif = eif0 + eif1, ego = ego0 + ego1;
        // eif.x=-l2e*i  eif.y=-l2e*f  ego.x=-2l2e*g  ego.y=-l2e*o
        const float Ai = fexp2(eif.x);                 // e^-i
        const float Fv = fexp2(eif.y);                 // e^-f
        const float Bg = fexp2(fminf(ego.x, 80.f));    // e^-2g (clamped: no inf*0)
        const float Ov = fexp2(ego.y);                 // e^-o
        const float sf = frcp(1.f + Fv);
        // -2l2e * sigmoid(i)*tanh(g) = (2l2e*Bg - 2l2e) / ((1+Ai)(1+Bg))
        const float it = fmaf(Bg, 2.f * L2E, -2.f * L2E) *
                         frcp((1.f + Ai) * (1.f + Bg));
        csv = fmaf(sf, csv, it);                       // csv = -2l2e * c
        const float Dv = fexp2(fminf(csv, 80.f));      // e^-2c (clamped)
        // sigmoid(o)*tanh(c) = (1-Dv) / ((1+Ov)(1+Dv))
        hv = (1.f - Dv) * frcp((1.f + Ov) * (1.f + Dv));
        aS = fmaf(sx, hv, aS);
    };

    for (int cn = 0; cn < nChunks; ++cn) {
        // ---- move prefetched rows to locals, issue next chunk's loads ----
        const float4 cA0 = pA[0], cA1 = pA[1], cA2 = pA[2], cA3 = pA[3];
        const float4 cB0 = pB[0], cB1 = pB[1], cB2 = pB[2], cB3 = pB[3];
        {
            const int nc = (cn + 1 < nChunks) ? cn + 1 : cn;
            const float4* a = rowp(s0A, nc);
            pA[0] = a[0]; pA[1] = a[1]; pA[2] = a[2]; pA[3] = a[3];
            const float4* bq = rowp(s0B, nc);
            pB[0] = bq[0]; pB[1] = bq[1]; pB[2] = bq[2]; pB[3] = bq[3];
        }
        // ---- producer: pair packed matvec, 40 rows (pk_fma) ----
        xbuf[pair][r * 4 + cc]     = cA3.x;
        xbuf[pair + 1][r * 4 + cc] = cB3.x;
        v2f vab[12];
        vab[0]  = (v2f){cA0.x, cB0.x}; vab[1]  = (v2f){cA0.y, cB0.y};
        vab[2]  = (v2f){cA0.z, cB0.z}; vab[3]  = (v2f){cA0.w, cB0.w};
        vab[4]  = (v2f){cA1.x, cB1.x}; vab[5]  = (v2f){cA1.y, cB1.y};
        vab[6]  = (v2f){cA1.z, cB1.z}; vab[7]  = (v2f){cA1.w, cB1.w};
        vab[8]  = (v2f){cA2.x, cB2.x}; vab[9]  = (v2f){cA2.y, cB2.y};
        vab[10] = (v2f){cA2.z, cB2.z}; vab[11] = (v2f){cA2.w, cB2.w};
        const int wb = (r * 4 + cc) * 44;
#pragma unroll 2
        for (int j = 0; j < 10; ++j) {
            float oA[4], oB[4];
#pragma unroll
            for (int g = 0; g < 4; ++g) {
                const int rr = g * 10 + j;
                const float4 w0 = *reinterpret_cast<const float4*>(&wbuf[rr * 16 + 0]);
                const float4 w1 = *reinterpret_cast<const float4*>(&wbuf[rr * 16 + 4]);
                const float4 w2 = *reinterpret_cast<const float4*>(&wbuf[rr * 16 + 8]);
                const float  bb = wbuf[rr * 16 + 12];
                v2f a0 = (v2f){bb, bb}, a1 = (v2f){0.f, 0.f};
                v2f a2 = (v2f){0.f, 0.f}, a3 = (v2f){0.f, 0.f};
                a0 += vab[0]  * (v2f){w0.x, w0.x}; a1 += vab[1]  * (v2f){w0.y, w0.y};
                a2 += vab[2]  * (v2f){w0.z, w0.z}; a3 += vab[3]  * (v2f){w0.w, w0.w};
                a0 += vab[4]  * (v2f){w1.x, w1.x}; a1 += vab[5]  * (v2f){w1.y, w1.y};
                a2 += vab[6]  * (v2f){w1.z, w1.z}; a3 += vab[7]  * (v2f){w1.w, w1.w};
                a0 += vab[8]  * (v2f){w2.x, w2.x}; a1 += vab[9]  * (v2f){w2.y, w2.y};
                a2 += vab[10] * (v2f){w2.z, w2.z}; a3 += vab[11] * (v2f){w2.w, w2.w};
                const v2f s = (a0 + a1) + (a2 + a3);
                oA[g] = s.x; oB[g] = s.y;
            }
            *reinterpret_cast<float4*>(&gbuf[pair][wb + j * 4]) =
                make_float4(oA[0], oA[1], oA[2], oA[3]);
            *reinterpret_cast<float4*>(&gbuf[pair + 1][wb + j * 4]) =
                make_float4(oB[0], oB[1], oB[2], oB[3]);
        }
        // ---- same-wave DS ordering (single wave: no barrier) ----
        asm volatile("s_waitcnt lgkmcnt(0)" ::: "memory");
        // ---- consume 8 interleaved 4-segment step groups ----
#pragma unroll 2
        for (int i = 0; i < 8; ++i) {
#pragma unroll
            for (int k = 0; k < 4; ++k)
                step(gbuf[k], xbuf[k], cs[k], hh[k], accS[k], i);
        }
        if (cn + 1 == warmChunks) {
            accS[0] = accS[1] = accS[2] = accS[3] = 0.f;  // drop warmup contrib
            if (q == 0) { cs[0] = 0.f; hh[0] = 0.f; }     // seg0: exact zero init
        }
    }

    // ---- group reduction (within 16-lane group; lane0 tree stays clean) ----
    float v[4];
#pragma unroll
    for (int k = 0; k < 4; ++k) v[k] = (jr < 10) ? accS[k] : 0.f;
#pragma unroll
    for (int off = 1; off <= 8; off <<= 1) {
#pragma unroll
        for (int k = 0; k < 4; ++k) v[k] += __shfl_down(v[k], off);
    }
    if (jr == 0) {
#pragma unroll
        for (int k = 0; k < 4; ++k)
            P[(4 * q + k) * 512 + d * 256 + b0 + c] = v[k];
    }
}

// ---------------------------------------------------------------------------
// Kernel 3: out[b] = sigmoid( sum over 32 segments x 2 directions )
// ---------------------------------------------------------------------------
__global__ __launch_bounds__(256) void final_kernel(const float* __restrict__ P,
                                                    float* __restrict__ out)
{
    const int b = threadIdx.x;
    float v = 0.f;
#pragma unroll
    for (int seg = 0; seg < 32; ++seg)
        v += P[seg * 512 + b] + P[seg * 512 + 256 + b];
    out[b] = frcp(1.f + fexp2(-v * L2E));
}

extern "C" void kernel_launch(void* const* d_in, const int* in_sizes, int n_in,
                              void* d_out, int out_size, void* d_ws, size_t ws_size,
                              hipStream_t stream)
{
    const float* x     = (const float*)d_in[0];
    const float* w4    = (const float*)d_in[1];
    const float* w5    = (const float*)d_in[2];
    const float* w6    = (const float*)d_in[3];
    const float* w7    = (const float*)d_in[4];
    const float* w8    = (const float*)d_in[5];
    const float* Wih_f = (const float*)d_in[6];
    const float* Whh_f = (const float*)d_in[7];
    const float* bih_f = (const float*)d_in[8];
    const float* bhh_f = (const float*)d_in[9];
    const float* Wih_r = (const float*)d_in[10];
    const float* Whh_r = (const float*)d_in[11];
    const float* bih_r = (const float*)d_in[12];
    const float* bhh_r = (const float*)d_in[13];

    // ws layout (fp32): lin [256][4096][16] (64MB) | P[16384] | MMu[1280] | Wp[1280]
    float*    lin = (float*)d_ws;
    float*    P   = lin + (size_t)NBATCH * SEQ * 16;
    unsigned* MMu = (unsigned*)(P + 32 * 512);
    float*    Wpp = (float*)(MMu + 1280);

    wprep_kernel<<<1, 256, 0, stream>>>(Wih_f, bih_f, bhh_f,
                                        Wih_r, bih_r, bhh_r, Wpp, MMu);
    max_kernel<<<4 * NBATCH, 256, 0, stream>>>(x, w4, w5, w6, w7, w8, MMu);
    scatter_kernel<<<4 * NBATCH, 256, 0, stream>>>(x, w4, w5, w6, w7, w8, MMu, lin);
    lstm_kernel<<<1024, 64, 0, stream>>>(lin, Wpp, Whh_f, Whh_r, P);
    final_kernel<<<1, NBATCH, 0, stream>>>(P, (float*)d_out);
}

// Round 2
// 277.100 us; speedup vs baseline: 1.4541x; 1.4541x over previous
//
#include <hip/hip_runtime.h>

#define SEQ 4096
#define NBATCH 256

typedef float v2f __attribute__((ext_vector_type(2)));

__device__ __forceinline__ float sqf(float v) { return v * v; }
__device__ __forceinline__ float fexp2(float v) { return __builtin_amdgcn_exp2f(v); }
__device__ __forceinline__ float frcp(float v)  { return __builtin_amdgcn_rcpf(v); }

#define L2E 1.4426950408889634f

// order-preserving float<->uint key for atomicMax on floats
__device__ __forceinline__ unsigned fkey(float f) {
    const int b = __float_as_int(f);
    return (unsigned)(b ^ ((b >> 31) | 0x80000000));
}
__device__ __forceinline__ float fival(unsigned k) {
    const int b = (k & 0x80000000u) ? (int)(k ^ 0x80000000u) : (int)(~k);
    return __int_as_float(b);
}

// ---------------------------------------------------------------------------
// Kernel 0: fold the 24-wide input matvec into 12 inputs + bias, pre-scaled
// by the row's activation pre-scale (-log2e; -2log2e for g rows).
// Also zero-initializes the MMu atomic-max buffer (re-poisoned every call).
// ---------------------------------------------------------------------------
__global__ void wprep_kernel(
    const float* __restrict__ Wih_f, const float* __restrict__ bih_f,
    const float* __restrict__ bhh_f,
    const float* __restrict__ Wih_r, const float* __restrict__ bih_r,
    const float* __restrict__ bhh_r,
    float* __restrict__ Wp, unsigned* __restrict__ MMu)
{
    const int t = threadIdx.x;
    for (int i = t; i < NBATCH * 5; i += 256) MMu[i] = 0u;  // key 0 < any real
    if (t >= 80) return;
    const int d = t / 40, r = t % 40;
    const float* __restrict__ W  = (d ? Wih_r : Wih_f) + r * 24;
    const float* __restrict__ bi = d ? bih_r : bih_f;
    const float* __restrict__ bh = d ? bhh_r : bhh_f;
    const float sc = (r >= 20 && r < 30) ? (-2.f * L2E) : (-L2E);
    float o[13];
    o[0]  = W[0] + W[1] + W[2] + W[3];                // v4s
    o[1]  = W[4] + W[5] + W[6] + W[7];                // v5s
    o[2]  = W[4];                                     // v5p
    o[3]  = W[8] + W[9] + W[10] + W[11];              // v6s
    o[4]  = W[8] + W[9];                              // v6p
    o[5]  = W[12] + W[13] + W[14] + W[15];            // v7s
    o[6]  = W[12] + W[13] + W[14];                    // v7p
    o[7]  = W[16] + W[17] + W[18] + W[19];            // v8s+v8p
    o[8]  = W[20]; o[9] = W[21]; o[10] = W[22]; o[11] = W[23];   // x0..x3
    o[12] = bi[r] + bh[r];
    float* __restrict__ out = Wp + (d * 40 + r) * 16;
#pragma unroll
    for (int k = 0; k < 13; ++k) out[k] = o[k] * sc;
    out[13] = 0.f; out[14] = 0.f; out[15] = 0.f;
}

// ---------------------------------------------------------------------------
// Kernel 1a: per-batch conv max -> atomicMax on uint keys.
// ---------------------------------------------------------------------------
__global__ __launch_bounds__(256) void max_kernel(
    const float* __restrict__ x,
    const float* __restrict__ w4p, const float* __restrict__ w5p,
    const float* __restrict__ w6p, const float* __restrict__ w7p,
    const float* __restrict__ w8p,
    unsigned* __restrict__ MMu)
{
    const int b    = blockIdx.x >> 2;
    const int quar = blockIdx.x & 3;
    const int tid  = threadIdx.x;
    const float* __restrict__ xr = x + (size_t)b * (4 * SEQ);

    float W4[4], W5[5], W6[6], W7[7], W8[8];
#pragma unroll
    for (int k = 0; k < 4; ++k) W4[k] = w4p[k];
#pragma unroll
    for (int k = 0; k < 5; ++k) W5[k] = w5p[k];
#pragma unroll
    for (int k = 0; k < 6; ++k) W6[k] = w6p[k];
#pragma unroll
    for (int k = 0; k < 7; ++k) W7[k] = w7p[k];
#pragma unroll
    for (int k = 0; k < 8; ++k) W8[k] = w8p[k];

    float m4 = -3.4e38f, m5 = -3.4e38f, m6 = -3.4e38f, m7 = -3.4e38f, m8 = -3.4e38f;
    for (int i = quar * (SEQ / 4) + tid; i < (quar + 1) * (SEQ / 4); i += 256) {
        const float4 t0 = *reinterpret_cast<const float4*>(xr + 4 * i);
        const float xa0 = t0.x, xa1 = t0.y, xa2 = t0.z, xa3 = t0.w;
        const float c4 = xa0 * W4[0] + xa1 * W4[1] + xa2 * W4[2] + xa3 * W4[3];
        m4 = fmaxf(m4, c4);
        if (i < SEQ - 1) {
            const float4 t1 = *reinterpret_cast<const float4*>(xr + 4 * i + 4);
            const float xa4 = t1.x, xa5 = t1.y, xa6 = t1.z, xa7 = t1.w;
            const float c5 = xa0*W5[0]+xa1*W5[1]+xa2*W5[2]+xa3*W5[3]+xa4*W5[4];
            const float c6 = xa0*W6[0]+xa1*W6[1]+xa2*W6[2]+xa3*W6[3]+xa4*W6[4]+xa5*W6[5];
            const float c7 = xa0*W7[0]+xa1*W7[1]+xa2*W7[2]+xa3*W7[3]+xa4*W7[4]+xa5*W7[5]+xa6*W7[6];
            const float c8 = xa0*W8[0]+xa1*W8[1]+xa2*W8[2]+xa3*W8[3]+xa4*W8[4]+xa5*W8[5]+xa6*W8[6]+xa7*W8[7];
            m5 = fmaxf(m5, c5); m6 = fmaxf(m6, c6);
            m7 = fmaxf(m7, c7); m8 = fmaxf(m8, c8);
        }
    }
#pragma unroll
    for (int off = 32; off; off >>= 1) {
        m4 = fmaxf(m4, __shfl_down(m4, off));
        m5 = fmaxf(m5, __shfl_down(m5, off));
        m6 = fmaxf(m6, __shfl_down(m6, off));
        m7 = fmaxf(m7, __shfl_down(m7, off));
        m8 = fmaxf(m8, __shfl_down(m8, off));
    }
    __shared__ float wr[4][5];
    if ((tid & 63) == 0) {
        const int w = tid >> 6;
        wr[w][0] = m4; wr[w][1] = m5; wr[w][2] = m6; wr[w][3] = m7; wr[w][4] = m8;
    }
    __syncthreads();
    if (tid < 5) {
        const float m = fmaxf(fmaxf(wr[0][tid], wr[1][tid]),
                              fmaxf(wr[2][tid], wr[3][tid]));
        atomicMax(&MMu[b * 5 + tid], fkey(m));
    }
}

// ---------------------------------------------------------------------------
// Kernel 1b: winner-takes-all -> compressed 12-input rows.
// lin[b][s][16] = {v4s, v5s, v5p, v6s, v6p, v7s, v7p, v8s+v8p,
//                  x0, x1, x2, x3, xsum, 0,0,0}
// ---------------------------------------------------------------------------
__global__ __launch_bounds__(256) void scatter_kernel(
    const float* __restrict__ x,
    const float* __restrict__ w4p, const float* __restrict__ w5p,
    const float* __restrict__ w6p, const float* __restrict__ w7p,
    const float* __restrict__ w8p,
    const unsigned* __restrict__ MMu,
    float* __restrict__ lin)
{
    const int b    = blockIdx.x >> 2;
    const int quar = blockIdx.x & 3;
    const int tid  = threadIdx.x;
    const float* __restrict__ xr = x + (size_t)b * (4 * SEQ);

    float W4[4], W5[5], W6[6], W7[7], W8[8];
#pragma unroll
    for (int k = 0; k < 4; ++k) W4[k] = w4p[k];
#pragma unroll
    for (int k = 0; k < 5; ++k) W5[k] = w5p[k];
#pragma unroll
    for (int k = 0; k < 6; ++k) W6[k] = w6p[k];
#pragma unroll
    for (int k = 0; k < 7; ++k) W7[k] = w7p[k];
#pragma unroll
    for (int k = 0; k < 8; ++k) W8[k] = w8p[k];

    const float M4 = fival(MMu[b * 5 + 0]), M5 = fival(MMu[b * 5 + 1]),
                M6 = fival(MMu[b * 5 + 2]), M7 = fival(MMu[b * 5 + 3]),
                M8 = fival(MMu[b * 5 + 4]);

    for (int s = quar * (SEQ / 4) + tid; s < (quar + 1) * (SEQ / 4); s += 256) {
        float xw[12];
        if (s > 0) {
            const float4 t = *reinterpret_cast<const float4*>(xr + 4 * s - 4);
            xw[0] = t.x; xw[1] = t.y; xw[2] = t.z; xw[3] = t.w;
        } else { xw[0] = xw[1] = xw[2] = xw[3] = 0.f; }
        {
            const float4 t = *reinterpret_cast<const float4*>(xr + 4 * s);
            xw[4] = t.x; xw[5] = t.y; xw[6] = t.z; xw[7] = t.w;
        }
        if (s < SEQ - 1) {
            const float4 t = *reinterpret_cast<const float4*>(xr + 4 * s + 4);
            xw[8] = t.x; xw[9] = t.y; xw[10] = t.z; xw[11] = t.w;
        } else { xw[8] = xw[9] = xw[10] = xw[11] = 0.f; }

        float c4s = 0.f, c5s = 0.f, c6s = 0.f, c7s = 0.f, c8s = 0.f;
        float c5p = 0.f, c6p = 0.f, c7p = 0.f, c8p = 0.f;
#pragma unroll
        for (int t = 0; t < 4; ++t) c4s += xw[4 + t] * W4[t];
#pragma unroll
        for (int t = 0; t < 5; ++t) { c5s += xw[4 + t] * W5[t]; c5p += xw[t] * W5[t]; }
#pragma unroll
        for (int t = 0; t < 6; ++t) { c6s += xw[4 + t] * W6[t]; c6p += xw[t] * W6[t]; }
#pragma unroll
        for (int t = 0; t < 7; ++t) { c7s += xw[4 + t] * W7[t]; c7p += xw[t] * W7[t]; }
#pragma unroll
        for (int t = 0; t < 8; ++t) { c8s += xw[4 + t] * W8[t]; c8p += xw[t] * W8[t]; }

        const bool oks = (s < SEQ - 1);
        const bool okp = (s > 0);
        const float v4s = sqf(c4s + M4);
        const float v5s = oks ? sqf(c5s + M5) : 0.f;
        const float v6s = oks ? sqf(c6s + M6) : 0.f;
        const float v7s = oks ? sqf(c7s + M7) : 0.f;
        const float v8s = oks ? sqf(c8s + M8) : 0.f;
        const float v5p = okp ? sqf(c5p + M5) : 0.f;
        const float v6p = okp ? sqf(c6p + M6) : 0.f;
        const float v7p = okp ? sqf(c7p + M7) : 0.f;
        const float v8p = okp ? sqf(c8p + M8) : 0.f;

        const float xsum = (xw[4] + xw[5]) + (xw[6] + xw[7]);
        float4* op = reinterpret_cast<float4*>(lin + ((size_t)b * SEQ + s) * 16);
        op[0] = make_float4(v4s, v5s, v5p, v6s);
        op[1] = make_float4(v6p, v7s, v7p, v8s + v8p);
        op[2] = make_float4(xw[4], xw[5], xw[6], xw[7]);
        op[3] = make_float4(xsum, 0.f, 0.f, 0.f);
    }
}

// ---------------------------------------------------------------------------
// Kernel 2: K=16 segmented bidirectional LSTM, 4 spatial chains x 2 temporal
// segments per wave. nseg=16, own=256, warm=128. Grid = 8q x 2d x 64bg =
// 1024 blocks x 64 thr = 1 wave/SIMD.
// r1 post-mortem: 4-way ILP left per-segstep wall EXACTLY unchanged (775 cy,
// VALUBusy 45%) -> throughput-bound on the per-CU LDS pipe, not latency.
// DS diet this round (566 -> ~214 DS ops/chunk):
//  (a) h broadcast via 10x ds_bpermute  ->  1x ds_write + 3x ds_read from a
//      per-seg hb[4][16] buffer (group-uniform addrs broadcast; 2-way bank
//      aliasing only, free per m136). h state now lives in LDS, not regs.
//  (b) producer weights: LDS wbuf -> uniform global loads from Wp (compiler
//      scalarizes to s_load; scalar cache, off the LDS pipe entirely).
// Warmup contraction (128 steps) + seg0 exact reset preserved; hb is zeroed
// at the reset so the LDS-resident h state is exact at s=0.
// ---------------------------------------------------------------------------
__global__ __launch_bounds__(64) void lstm_kernel(
    const float* __restrict__ lin,
    const float* __restrict__ Wp,
    const float* __restrict__ Whh_f,
    const float* __restrict__ Whh_r,
    float* __restrict__ P)
{
    const int bg   = blockIdx.x & 63;
    const int d    = (blockIdx.x >> 6) & 1;
    const int q    = blockIdx.x >> 7;          // 0..7
    const int b0   = bg * 4;
    const int lane = threadIdx.x;

    const int segA = 2 * q, segB = 2 * q + 1;
    const int s0A = segA * 256 - 128;          // may be negative for q=0
    const int s0B = segB * 256 - 128;
    const int nChunks = 24, warmChunks = 8;    // 16-step chunks, 384 steps

    __shared__ float gbufA[16 * 4 * 44];
    __shared__ float gbufB[16 * 4 * 44];
    __shared__ float xbufA[64];
    __shared__ float xbufB[64];
    __shared__ float hbA[64];                  // [chain][16] broadcast h
    __shared__ float hbB[64];

    // ---- consumer setup: c = lane>>4 (chain), jr = lane&15 (unit) ----
    const int c   = lane >> 4;
    const int jr  = lane & 15;
    const int jc  = (jr < 10) ? jr : 0;

    hbA[lane] = 0.f;                           // lane == c*16+jr
    hbB[lane] = 0.f;

    const float* __restrict__ Whh = d ? Whh_r : Whh_f;
    v2f wIF[10], wGO[10];
#pragma unroll
    for (int k = 0; k < 10; ++k) {
        wIF[k] = (v2f){Whh[jc * 10 + k]        * (-L2E),
                       Whh[(10 + jc) * 10 + k] * (-L2E)};
        wGO[k] = (v2f){Whh[(20 + jc) * 10 + k] * (-2.f * L2E),
                       Whh[(30 + jc) * 10 + k] * (-L2E)};
    }

    // producer weights: uniform global pointer (scalarized loads)
    const float* __restrict__ Wd = Wp + d * 640;

    // ---- producer setup: cc = lane&3 (chain), r = lane>>2 (step) ----
    const int cc = lane & 3;
    const int r  = lane >> 2;                  // 0..15
    const float* __restrict__ chbase = lin + (size_t)(b0 + cc) * SEQ * 16;

    auto rowp = [&](int s0, int cn) {
        int sp = s0 + cn * 16 + r;
        if (sp < 0) sp = 0;                    // q=0 warm region: clamped garbage,
                                               // discarded by the state reset
        const int pos = d ? (SEQ - 1 - sp) : sp;
        return reinterpret_cast<const float4*>(chbase + (size_t)pos * 16);
    };

    float4 pA[4], pB[4];
    {
        const float4* a = rowp(s0A, 0);
        pA[0] = a[0]; pA[1] = a[1]; pA[2] = a[2]; pA[3] = a[3];
        const float4* bq = rowp(s0B, 0);
        pB[0] = bq[0]; pB[1] = bq[1]; pB[2] = bq[2]; pB[3] = bq[3];
    }

    float csA = 0.f, accSA = 0.f;
    float csB = 0.f, accSB = 0.f;

    // one recurrence step (consumer); h state round-trips through hb in LDS
    auto step = [&](const float* gb, const float* xb, float* hb,
                    float& csv, float& aS, int i) {
        const float4 gp4 =
            *reinterpret_cast<const float4*>(&gb[(i * 4 + c) * 44 + jc * 4]);
        const float sx = xb[i * 4 + c];
        const float4 h03 = *reinterpret_cast<const float4*>(&hb[c * 16 + 0]);
        const float4 h47 = *reinterpret_cast<const float4*>(&hb[c * 16 + 4]);
        const float2 h89 = *reinterpret_cast<const float2*>(&hb[c * 16 + 8]);
        const float hj[10] = {h03.x, h03.y, h03.z, h03.w,
                              h47.x, h47.y, h47.z, h47.w, h89.x, h89.y};
        v2f eif0 = (v2f){gp4.x, gp4.y}, eif1 = (v2f){0.f, 0.f};
        v2f ego0 = (v2f){gp4.z, gp4.w}, ego1 = (v2f){0.f, 0.f};
#pragma unroll
        for (int k = 0; k < 10; k += 2) {
            const v2f h0 = (v2f){hj[k], hj[k]};
            const v2f h1 = (v2f){hj[k + 1], hj[k + 1]};
            eif0 += h0 * wIF[k]; eif1 += h1 * wIF[k + 1];
            ego0 += h0 * wGO[k]; ego1 += h1 * wGO[k + 1];
        }
        const v2f eif = eif0 + eif1, ego = ego0 + ego1;
        // eif.x=-l2e*i  eif.y=-l2e*f  ego.x=-2l2e*g  ego.y=-l2e*o
        const float Ai = fexp2(eif.x);                 // e^-i
        const float Fv = fexp2(eif.y);                 // e^-f
        const float Bg = fexp2(fminf(ego.x, 80.f));    // e^-2g (clamped: no inf*0)
        const float Ov = fexp2(ego.y);                 // e^-o
        const float sf = frcp(1.f + Fv);
        // -2l2e * sigmoid(i)*tanh(g) = (2l2e*Bg - 2l2e) / ((1+Ai)(1+Bg))
        const float it = fmaf(Bg, 2.f * L2E, -2.f * L2E) *
                         frcp((1.f + Ai) * (1.f + Bg));
        csv = fmaf(sf, csv, it);                       // csv = -2l2e * c
        const float Dv = fexp2(fminf(csv, 80.f));      // e^-2c (clamped)
        // sigmoid(o)*tanh(c) = (1-Dv) / ((1+Ov)(1+Dv))
        const float hv = (1.f - Dv) * frcp((1.f + Ov) * (1.f + Dv));
        hb[c * 16 + jr] = hv;                          // jr>=10 -> harmless pad
        aS = fmaf(sx, hv, aS);
    };

    for (int cn = 0; cn < nChunks; ++cn) {
        // ---- move prefetched rows to locals, issue next chunk's loads ----
        const float4 cA0 = pA[0], cA1 = pA[1], cA2 = pA[2], cA3 = pA[3];
        const float4 cB0 = pB[0], cB1 = pB[1], cB2 = pB[2], cB3 = pB[3];
        {
            const int nc = (cn + 1 < nChunks) ? cn + 1 : cn;
            const float4* a = rowp(s0A, nc);
            pA[0] = a[0]; pA[1] = a[1]; pA[2] = a[2]; pA[3] = a[3];
            const float4* bq = rowp(s0B, nc);
            pB[0] = bq[0]; pB[1] = bq[1]; pB[2] = bq[2]; pB[3] = bq[3];
        }
        // ---- producer: A/B packed matvec, 40 rows (pk_fma) ----
        xbufA[r * 4 + cc] = cA3.x;
        xbufB[r * 4 + cc] = cB3.x;
        v2f vab[12];
        vab[0]  = (v2f){cA0.x, cB0.x}; vab[1]  = (v2f){cA0.y, cB0.y};
        vab[2]  = (v2f){cA0.z, cB0.z}; vab[3]  = (v2f){cA0.w, cB0.w};
        vab[4]  = (v2f){cA1.x, cB1.x}; vab[5]  = (v2f){cA1.y, cB1.y};
        vab[6]  = (v2f){cA1.z, cB1.z}; vab[7]  = (v2f){cA1.w, cB1.w};
        vab[8]  = (v2f){cA2.x, cB2.x}; vab[9]  = (v2f){cA2.y, cB2.y};
        vab[10] = (v2f){cA2.z, cB2.z}; vab[11] = (v2f){cA2.w, cB2.w};
        const int wb = (r * 4 + cc) * 44;
#pragma unroll 2
        for (int j = 0; j < 10; ++j) {
            float oA[4], oB[4];
#pragma unroll
            for (int g = 0; g < 4; ++g) {
                const int rr = g * 10 + j;
                const float4 w0 = *reinterpret_cast<const float4*>(Wd + rr * 16 + 0);
                const float4 w1 = *reinterpret_cast<const float4*>(Wd + rr * 16 + 4);
                const float4 w2 = *reinterpret_cast<const float4*>(Wd + rr * 16 + 8);
                const float  bb = Wd[rr * 16 + 12];
                v2f a0 = (v2f){bb, bb}, a1 = (v2f){0.f, 0.f};
                v2f a2 = (v2f){0.f, 0.f}, a3 = (v2f){0.f, 0.f};
                a0 += vab[0]  * (v2f){w0.x, w0.x}; a1 += vab[1]  * (v2f){w0.y, w0.y};
                a2 += vab[2]  * (v2f){w0.z, w0.z}; a3 += vab[3]  * (v2f){w0.w, w0.w};
                a0 += vab[4]  * (v2f){w1.x, w1.x}; a1 += vab[5]  * (v2f){w1.y, w1.y};
                a2 += vab[6]  * (v2f){w1.z, w1.z}; a3 += vab[7]  * (v2f){w1.w, w1.w};
                a0 += vab[8]  * (v2f){w2.x, w2.x}; a1 += vab[9]  * (v2f){w2.y, w2.y};
                a2 += vab[10] * (v2f){w2.z, w2.z}; a3 += vab[11] * (v2f){w2.w, w2.w};
                const v2f s = (a0 + a1) + (a2 + a3);
                oA[g] = s.x; oB[g] = s.y;
            }
            *reinterpret_cast<float4*>(&gbufA[wb + j * 4]) =
                make_float4(oA[0], oA[1], oA[2], oA[3]);
            *reinterpret_cast<float4*>(&gbufB[wb + j * 4]) =
                make_float4(oB[0], oB[1], oB[2], oB[3]);
        }
        // ---- same-wave DS ordering (single wave: no barrier) ----
        asm volatile("s_waitcnt lgkmcnt(0)" ::: "memory");
        // ---- consume 16 interleaved A/B step pairs ----
#pragma unroll 4
        for (int i = 0; i < 16; ++i) {
            step(gbufA, xbufA, hbA, csA, accSA, i);
            step(gbufB, xbufB, hbB, csB, accSB, i);
        }
        if (cn + 1 == warmChunks) {
            accSA = 0.f; accSB = 0.f;          // drop warmup contributions
            if (q == 0) {                      // seg0: exact zero init at s=0
                csA = 0.f;
                hbA[lane] = 0.f;
            }
        }
    }

    // ---- group reduction (within 16-lane group; lane0 tree stays clean) ----
    float vA = (jr < 10) ? accSA : 0.f;
    float vB = (jr < 10) ? accSB : 0.f;
#pragma unroll
    for (int off = 1; off <= 8; off <<= 1) {
        vA += __shfl_down(vA, off);
        vB += __shfl_down(vB, off);
    }
    if (jr == 0) {
        P[segA * 512 + d * 256 + b0 + c] = vA;
        P[segB * 512 + d * 256 + b0 + c] = vB;
    }
}

// ---------------------------------------------------------------------------
// Kernel 3: out[b] = sigmoid( sum over 16 segments x 2 directions )
// ---------------------------------------------------------------------------
__global__ __launch_bounds__(256) void final_kernel(const float* __restrict__ P,
                                                    float* __restrict__ out)
{
    const int b = threadIdx.x;
    float v = 0.f;
#pragma unroll
    for (int seg = 0; seg < 16; ++seg)
        v += P[seg * 512 + b] + P[seg * 512 + 256 + b];
    out[b] = frcp(1.f + fexp2(-v * L2E));
}

extern "C" void kernel_launch(void* const* d_in, const int* in_sizes, int n_in,
                              void* d_out, int out_size, void* d_ws, size_t ws_size,
                              hipStream_t stream)
{
    const float* x     = (const float*)d_in[0];
    const float* w4    = (const float*)d_in[1];
    const float* w5    = (const float*)d_in[2];
    const float* w6    = (const float*)d_in[3];
    const float* w7    = (const float*)d_in[4];
    const float* w8    = (const float*)d_in[5];
    const float* Wih_f = (const float*)d_in[6];
    const float* Whh_f = (const float*)d_in[7];
    const float* bih_f = (const float*)d_in[8];
    const float* bhh_f = (const float*)d_in[9];
    const float* Wih_r = (const float*)d_in[10];
    const float* Whh_r = (const float*)d_in[11];
    const float* bih_r = (const float*)d_in[12];
    const float* bhh_r = (const float*)d_in[13];

    // ws layout (fp32): lin [256][4096][16] (64MB) | P[8192] | MMu[1280] | Wp[1280]
    float*    lin = (float*)d_ws;
    float*    P   = lin + (size_t)NBATCH * SEQ * 16;
    unsigned* MMu = (unsigned*)(P + 8192);
    float*    Wpp = (float*)(MMu + 1280);

    wprep_kernel<<<1, 256, 0, stream>>>(Wih_f, bih_f, bhh_f,
                                        Wih_r, bih_r, bhh_r, Wpp, MMu);
    max_kernel<<<4 * NBATCH, 256, 0, stream>>>(x, w4, w5, w6, w7, w8, MMu);
    scatter_kernel<<<4 * NBATCH, 256, 0, stream>>>(x, w4, w5, w6, w7, w8, MMu, lin);
    lstm_kernel<<<1024, 64, 0, stream>>>(lin, Wpp, Whh_f, Whh_r, P);
    final_kernel<<<1, NBATCH, 0, stream>>>(P, (float*)d_out);
}

// Round 3
// 269.579 us; speedup vs baseline: 1.4947x; 1.0279x over previous
//
#include <hip/hip_runtime.h>

#define SEQ 4096
#define NBATCH 256

typedef float v2f __attribute__((ext_vector_type(2)));

__device__ __forceinline__ float sqf(float v) { return v * v; }
__device__ __forceinline__ float fexp2(float v) { return __builtin_amdgcn_exp2f(v); }
__device__ __forceinline__ float frcp(float v)  { return __builtin_amdgcn_rcpf(v); }

#define L2E 1.4426950408889634f

// order-preserving float<->uint key for atomicMax on floats
__device__ __forceinline__ unsigned fkey(float f) {
    const int b = __float_as_int(f);
    return (unsigned)(b ^ ((b >> 31) | 0x80000000));
}
__device__ __forceinline__ float fival(unsigned k) {
    const int b = (k & 0x80000000u) ? (int)(k ^ 0x80000000u) : (int)(~k);
    return __int_as_float(b);
}

// ---------------------------------------------------------------------------
// Kernel 0: fold the 24-wide input matvec into 12 inputs + bias, pre-scaled
// by the row's activation pre-scale (-log2e; -2log2e for g rows).
// Also zero-initializes the MMu atomic-max buffer (re-poisoned every call).
// ---------------------------------------------------------------------------
__global__ void wprep_kernel(
    const float* __restrict__ Wih_f, const float* __restrict__ bih_f,
    const float* __restrict__ bhh_f,
    const float* __restrict__ Wih_r, const float* __restrict__ bih_r,
    const float* __restrict__ bhh_r,
    float* __restrict__ Wp, unsigned* __restrict__ MMu)
{
    const int t = threadIdx.x;
    for (int i = t; i < NBATCH * 5; i += 256) MMu[i] = 0u;  // key 0 < any real
    if (t >= 80) return;
    const int d = t / 40, r = t % 40;
    const float* __restrict__ W  = (d ? Wih_r : Wih_f) + r * 24;
    const float* __restrict__ bi = d ? bih_r : bih_f;
    const float* __restrict__ bh = d ? bhh_r : bhh_f;
    const float sc = (r >= 20 && r < 30) ? (-2.f * L2E) : (-L2E);
    float o[13];
    o[0]  = W[0] + W[1] + W[2] + W[3];                // v4s
    o[1]  = W[4] + W[5] + W[6] + W[7];                // v5s
    o[2]  = W[4];                                     // v5p
    o[3]  = W[8] + W[9] + W[10] + W[11];              // v6s
    o[4]  = W[8] + W[9];                              // v6p
    o[5]  = W[12] + W[13] + W[14] + W[15];            // v7s
    o[6]  = W[12] + W[13] + W[14];                    // v7p
    o[7]  = W[16] + W[17] + W[18] + W[19];            // v8s+v8p
    o[8]  = W[20]; o[9] = W[21]; o[10] = W[22]; o[11] = W[23];   // x0..x3
    o[12] = bi[r] + bh[r];
    float* __restrict__ out = Wp + (d * 40 + r) * 16;
#pragma unroll
    for (int k = 0; k < 13; ++k) out[k] = o[k] * sc;
    out[13] = 0.f; out[14] = 0.f; out[15] = 0.f;
}

// ---------------------------------------------------------------------------
// Kernel 1a: per-batch conv max -> atomicMax on uint keys.
// ---------------------------------------------------------------------------
__global__ __launch_bounds__(256) void max_kernel(
    const float* __restrict__ x,
    const float* __restrict__ w4p, const float* __restrict__ w5p,
    const float* __restrict__ w6p, const float* __restrict__ w7p,
    const float* __restrict__ w8p,
    unsigned* __restrict__ MMu)
{
    const int b    = blockIdx.x >> 2;
    const int quar = blockIdx.x & 3;
    const int tid  = threadIdx.x;
    const float* __restrict__ xr = x + (size_t)b * (4 * SEQ);

    float W4[4], W5[5], W6[6], W7[7], W8[8];
#pragma unroll
    for (int k = 0; k < 4; ++k) W4[k] = w4p[k];
#pragma unroll
    for (int k = 0; k < 5; ++k) W5[k] = w5p[k];
#pragma unroll
    for (int k = 0; k < 6; ++k) W6[k] = w6p[k];
#pragma unroll
    for (int k = 0; k < 7; ++k) W7[k] = w7p[k];
#pragma unroll
    for (int k = 0; k < 8; ++k) W8[k] = w8p[k];

    float m4 = -3.4e38f, m5 = -3.4e38f, m6 = -3.4e38f, m7 = -3.4e38f, m8 = -3.4e38f;
    for (int i = quar * (SEQ / 4) + tid; i < (quar + 1) * (SEQ / 4); i += 256) {
        const float4 t0 = *reinterpret_cast<const float4*>(xr + 4 * i);
        const float xa0 = t0.x, xa1 = t0.y, xa2 = t0.z, xa3 = t0.w;
        const float c4 = xa0 * W4[0] + xa1 * W4[1] + xa2 * W4[2] + xa3 * W4[3];
        m4 = fmaxf(m4, c4);
        if (i < SEQ - 1) {
            const float4 t1 = *reinterpret_cast<const float4*>(xr + 4 * i + 4);
            const float xa4 = t1.x, xa5 = t1.y, xa6 = t1.z, xa7 = t1.w;
            const float c5 = xa0*W5[0]+xa1*W5[1]+xa2*W5[2]+xa3*W5[3]+xa4*W5[4];
            const float c6 = xa0*W6[0]+xa1*W6[1]+xa2*W6[2]+xa3*W6[3]+xa4*W6[4]+xa5*W6[5];
            const float c7 = xa0*W7[0]+xa1*W7[1]+xa2*W7[2]+xa3*W7[3]+xa4*W7[4]+xa5*W7[5]+xa6*W7[6];
            const float c8 = xa0*W8[0]+xa1*W8[1]+xa2*W8[2]+xa3*W8[3]+xa4*W8[4]+xa5*W8[5]+xa6*W8[6]+xa7*W8[7];
            m5 = fmaxf(m5, c5); m6 = fmaxf(m6, c6);
            m7 = fmaxf(m7, c7); m8 = fmaxf(m8, c8);
        }
    }
#pragma unroll
    for (int off = 32; off; off >>= 1) {
        m4 = fmaxf(m4, __shfl_down(m4, off));
        m5 = fmaxf(m5, __shfl_down(m5, off));
        m6 = fmaxf(m6, __shfl_down(m6, off));
        m7 = fmaxf(m7, __shfl_down(m7, off));
        m8 = fmaxf(m8, __shfl_down(m8, off));
    }
    __shared__ float wr[4][5];
    if ((tid & 63) == 0) {
        const int w = tid >> 6;
        wr[w][0] = m4; wr[w][1] = m5; wr[w][2] = m6; wr[w][3] = m7; wr[w][4] = m8;
    }
    __syncthreads();
    if (tid < 5) {
        const float m = fmaxf(fmaxf(wr[0][tid], wr[1][tid]),
                              fmaxf(wr[2][tid], wr[3][tid]));
        atomicMax(&MMu[b * 5 + tid], fkey(m));
    }
}

// ---------------------------------------------------------------------------
// Kernel 1b: winner-takes-all -> compressed 12-input rows.
// lin[b][s][16] = {v4s, v5s, v5p, v6s, v6p, v7s, v7p, v8s+v8p,
//                  x0, x1, x2, x3, xsum, 0,0,0}
// ---------------------------------------------------------------------------
__global__ __launch_bounds__(256) void scatter_kernel(
    const float* __restrict__ x,
    const float* __restrict__ w4p, const float* __restrict__ w5p,
    const float* __restrict__ w6p, const float* __restrict__ w7p,
    const float* __restrict__ w8p,
    const unsigned* __restrict__ MMu,
    float* __restrict__ lin)
{
    const int b    = blockIdx.x >> 2;
    const int quar = blockIdx.x & 3;
    const int tid  = threadIdx.x;
    const float* __restrict__ xr = x + (size_t)b * (4 * SEQ);

    float W4[4], W5[5], W6[6], W7[7], W8[8];
#pragma unroll
    for (int k = 0; k < 4; ++k) W4[k] = w4p[k];
#pragma unroll
    for (int k = 0; k < 5; ++k) W5[k] = w5p[k];
#pragma unroll
    for (int k = 0; k < 6; ++k) W6[k] = w6p[k];
#pragma unroll
    for (int k = 0; k < 7; ++k) W7[k] = w7p[k];
#pragma unroll
    for (int k = 0; k < 8; ++k) W8[k] = w8p[k];

    const float M4 = fival(MMu[b * 5 + 0]), M5 = fival(MMu[b * 5 + 1]),
                M6 = fival(MMu[b * 5 + 2]), M7 = fival(MMu[b * 5 + 3]),
                M8 = fival(MMu[b * 5 + 4]);

    for (int s = quar * (SEQ / 4) + tid; s < (quar + 1) * (SEQ / 4); s += 256) {
        float xw[12];
        if (s > 0) {
            const float4 t = *reinterpret_cast<const float4*>(xr + 4 * s - 4);
            xw[0] = t.x; xw[1] = t.y; xw[2] = t.z; xw[3] = t.w;
        } else { xw[0] = xw[1] = xw[2] = xw[3] = 0.f; }
        {
            const float4 t = *reinterpret_cast<const float4*>(xr + 4 * s);
            xw[4] = t.x; xw[5] = t.y; xw[6] = t.z; xw[7] = t.w;
        }
        if (s < SEQ - 1) {
            const float4 t = *reinterpret_cast<const float4*>(xr + 4 * s + 4);
            xw[8] = t.x; xw[9] = t.y; xw[10] = t.z; xw[11] = t.w;
        } else { xw[8] = xw[9] = xw[10] = xw[11] = 0.f; }

        float c4s = 0.f, c5s = 0.f, c6s = 0.f, c7s = 0.f, c8s = 0.f;
        float c5p = 0.f, c6p = 0.f, c7p = 0.f, c8p = 0.f;
#pragma unroll
        for (int t = 0; t < 4; ++t) c4s += xw[4 + t] * W4[t];
#pragma unroll
        for (int t = 0; t < 5; ++t) { c5s += xw[4 + t] * W5[t]; c5p += xw[t] * W5[t]; }
#pragma unroll
        for (int t = 0; t < 6; ++t) { c6s += xw[4 + t] * W6[t]; c6p += xw[t] * W6[t]; }
#pragma unroll
        for (int t = 0; t < 7; ++t) { c7s += xw[4 + t] * W7[t]; c7p += xw[t] * W7[t]; }
#pragma unroll
        for (int t = 0; t < 8; ++t) { c8s += xw[4 + t] * W8[t]; c8p += xw[t] * W8[t]; }

        const bool oks = (s < SEQ - 1);
        const bool okp = (s > 0);
        const float v4s = sqf(c4s + M4);
        const float v5s = oks ? sqf(c5s + M5) : 0.f;
        const float v6s = oks ? sqf(c6s + M6) : 0.f;
        const float v7s = oks ? sqf(c7s + M7) : 0.f;
        const float v8s = oks ? sqf(c8s + M8) : 0.f;
        const float v5p = okp ? sqf(c5p + M5) : 0.f;
        const float v6p = okp ? sqf(c6p + M6) : 0.f;
        const float v7p = okp ? sqf(c7p + M7) : 0.f;
        const float v8p = okp ? sqf(c8p + M8) : 0.f;

        const float xsum = (xw[4] + xw[5]) + (xw[6] + xw[7]);
        float4* op = reinterpret_cast<float4*>(lin + ((size_t)b * SEQ + s) * 16);
        op[0] = make_float4(v4s, v5s, v5p, v6s);
        op[1] = make_float4(v6p, v7s, v7p, v8s + v8p);
        op[2] = make_float4(xw[4], xw[5], xw[6], xw[7]);
        op[3] = make_float4(xsum, 0.f, 0.f, 0.f);
    }
}

// ---------------------------------------------------------------------------
// Kernel 2: K=16 segmented bidirectional LSTM, 4 spatial chains x ONE
// temporal segment per wave. nseg=16, own=256, warm=128 (totals unchanged
// vs r2). Grid = 16 seg x 2 dir x 64 bgroups = 2048 blocks x 64 thr =
// 2 waves/SIMD (r2 post-mortem: at 1 wave/SIMD, VALUBusy 57% and the
// remaining 43% is un-hideable latency -- h LDS round-trip + s_load --
// so double TLP at constant total work instead of adding per-wave ILP).
// LDS 11.8KB/block -> 8 blocks/CU, exactly 2 waves/SIMD.
// Producer v2f packing switched from (segA,segB) pairs to GATE pairs:
// rows (j,10+j) and (20+j,30+j) share one output float4 -- identical
// pk_fma count per segment, identical gbuf layout as r2.
// DS diet from r2 kept: h via hb[] broadcast reads (no bpermute), producer
// weights via scalarized global s_loads (off the LDS pipe).
// Warmup contraction (128 steps) + seg0 exact reset preserved.
// ---------------------------------------------------------------------------
__global__ __launch_bounds__(64, 2) void lstm_kernel(
    const float* __restrict__ lin,
    const float* __restrict__ Wp,
    const float* __restrict__ Whh_f,
    const float* __restrict__ Whh_r,
    float* __restrict__ P)
{
    const int bg   = blockIdx.x & 63;
    const int d    = (blockIdx.x >> 6) & 1;
    const int q    = blockIdx.x >> 7;          // 0..15 = segment
    const int b0   = bg * 4;
    const int lane = threadIdx.x;

    const int s0 = q * 256 - 128;              // negative for q=0 (clamped)
    const int nChunks = 24, warmChunks = 8;    // 16-step chunks, 384 steps

    __shared__ float gbuf[16 * 4 * 44];
    __shared__ float xbuf[64];
    __shared__ float hb[64];                   // [chain][16] broadcast h

    // ---- consumer setup: c = lane>>4 (chain), jr = lane&15 (unit) ----
    const int c   = lane >> 4;
    const int jr  = lane & 15;
    const int jc  = (jr < 10) ? jr : 0;

    hb[lane] = 0.f;                            // lane == c*16+jr

    const float* __restrict__ Whh = d ? Whh_r : Whh_f;
    v2f wIF[10], wGO[10];
#pragma unroll
    for (int k = 0; k < 10; ++k) {
        wIF[k] = (v2f){Whh[jc * 10 + k]        * (-L2E),
                       Whh[(10 + jc) * 10 + k] * (-L2E)};
        wGO[k] = (v2f){Whh[(20 + jc) * 10 + k] * (-2.f * L2E),
                       Whh[(30 + jc) * 10 + k] * (-L2E)};
    }

    // producer weights: uniform global pointer (scalarized loads)
    const float* __restrict__ Wd = Wp + d * 640;

    // ---- producer setup: cc = lane&3 (chain), r = lane>>2 (step) ----
    const int cc = lane & 3;
    const int r  = lane >> 2;                  // 0..15
    const float* __restrict__ chbase = lin + (size_t)(b0 + cc) * SEQ * 16;

    auto rowp = [&](int cn) {
        int sp = s0 + cn * 16 + r;
        if (sp < 0) sp = 0;                    // q=0 warm region: clamped garbage,
                                               // discarded by the state reset
        const int pos = d ? (SEQ - 1 - sp) : sp;
        return reinterpret_cast<const float4*>(chbase + (size_t)pos * 16);
    };

    float4 pA[4];
    {
        const float4* a = rowp(0);
        pA[0] = a[0]; pA[1] = a[1]; pA[2] = a[2]; pA[3] = a[3];
    }

    float cs = 0.f, accS = 0.f;

    // one recurrence step (consumer); h state round-trips through hb in LDS
    auto step = [&](int i) {
        const float4 gp4 =
            *reinterpret_cast<const float4*>(&gbuf[(i * 4 + c) * 44 + jc * 4]);
        const float sx = xbuf[i * 4 + c];
        const float4 h03 = *reinterpret_cast<const float4*>(&hb[c * 16 + 0]);
        const float4 h47 = *reinterpret_cast<const float4*>(&hb[c * 16 + 4]);
        const float2 h89 = *reinterpret_cast<const float2*>(&hb[c * 16 + 8]);
        const float hj[10] = {h03.x, h03.y, h03.z, h03.w,
                              h47.x, h47.y, h47.z, h47.w, h89.x, h89.y};
        v2f eif0 = (v2f){gp4.x, gp4.y}, eif1 = (v2f){0.f, 0.f};
        v2f ego0 = (v2f){gp4.z, gp4.w}, ego1 = (v2f){0.f, 0.f};
#pragma unroll
        for (int k = 0; k < 10; k += 2) {
            const v2f h0 = (v2f){hj[k], hj[k]};
            const v2f h1 = (v2f){hj[k + 1], hj[k + 1]};
            eif0 += h0 * wIF[k]; eif1 += h1 * wIF[k + 1];
            ego0 += h0 * wGO[k]; ego1 += h1 * wGO[k + 1];
        }
        const v2f eif = eif0 + eif1, ego = ego0 + ego1;
        // eif.x=-l2e*i  eif.y=-l2e*f  ego.x=-2l2e*g  ego.y=-l2e*o
        const float Ai = fexp2(eif.x);                 // e^-i
        const float Fv = fexp2(eif.y);                 // e^-f
        const float Bg = fexp2(fminf(ego.x, 80.f));    // e^-2g (clamped: no inf*0)
        const float Ov = fexp2(ego.y);                 // e^-o
        const float sf = frcp(1.f + Fv);
        // -2l2e * sigmoid(i)*tanh(g) = (2l2e*Bg - 2l2e) / ((1+Ai)(1+Bg))
        const float it = fmaf(Bg, 2.f * L2E, -2.f * L2E) *
                         frcp((1.f + Ai) * (1.f + Bg));
        cs = fmaf(sf, cs, it);                         // cs = -2l2e * c
        const float Dv = fexp2(fminf(cs, 80.f));       // e^-2c (clamped)
        // sigmoid(o)*tanh(c) = (1-Dv) / ((1+Ov)(1+Dv))
        const float hv = (1.f - Dv) * frcp((1.f + Ov) * (1.f + Dv));
        hb[c * 16 + jr] = hv;                          // jr>=10 -> harmless pad
        accS = fmaf(sx, hv, accS);
    };

    for (int cn = 0; cn < nChunks; ++cn) {
        // ---- move prefetched rows to locals, issue next chunk's loads ----
        const float4 cA0 = pA[0], cA1 = pA[1], cA2 = pA[2], cA3 = pA[3];
        {
            const int nc = (cn + 1 < nChunks) ? cn + 1 : cn;
            const float4* a = rowp(nc);
            pA[0] = a[0]; pA[1] = a[1]; pA[2] = a[2]; pA[3] = a[3];
        }
        // ---- producer: gate-pair packed matvec, 40 rows (pk_fma) ----
        xbuf[r * 4 + cc] = cA3.x;
        float vv[12];
        vv[0] = cA0.x; vv[1] = cA0.y; vv[2]  = cA0.z; vv[3]  = cA0.w;
        vv[4] = cA1.x; vv[5] = cA1.y; vv[6]  = cA1.z; vv[7]  = cA1.w;
        vv[8] = cA2.x; vv[9] = cA2.y; vv[10] = cA2.z; vv[11] = cA2.w;
        const int wb = (r * 4 + cc) * 44;
#pragma unroll 2
        for (int j = 0; j < 10; ++j) {
            const float* __restrict__ R0 = Wd + j * 16;          // gate i, unit j
            const float* __restrict__ R1 = Wd + (10 + j) * 16;   // gate f
            const float* __restrict__ R2 = Wd + (20 + j) * 16;   // gate g
            const float* __restrict__ R3 = Wd + (30 + j) * 16;   // gate o
            v2f a01 = (v2f){R0[12], R1[12]}, b01 = (v2f){0.f, 0.f};
            v2f a23 = (v2f){R2[12], R3[12]}, b23 = (v2f){0.f, 0.f};
#pragma unroll
            for (int k = 0; k < 12; k += 2) {
                const v2f vk0 = (v2f){vv[k], vv[k]};
                const v2f vk1 = (v2f){vv[k + 1], vv[k + 1]};
                a01 += vk0 * (v2f){R0[k], R1[k]};
                b01 += vk1 * (v2f){R0[k + 1], R1[k + 1]};
                a23 += vk0 * (v2f){R2[k], R3[k]};
                b23 += vk1 * (v2f){R2[k + 1], R3[k + 1]};
            }
            const v2f s01 = a01 + b01, s23 = a23 + b23;
            *reinterpret_cast<float4*>(&gbuf[wb + j * 4]) =
                make_float4(s01.x, s01.y, s23.x, s23.y);
        }
        // ---- same-wave DS ordering (single wave: no barrier) ----
        asm volatile("s_waitcnt lgkmcnt(0)" ::: "memory");
        // ---- consume 16 steps (serial chain; TLP hides latency) ----
#pragma unroll 4
        for (int i = 0; i < 16; ++i) step(i);
        if (cn + 1 == warmChunks) {
            accS = 0.f;                        // drop warmup contributions
            if (q == 0) {                      // seg0: exact zero init at s=0
                cs = 0.f;
                hb[lane] = 0.f;
            }
        }
    }

    // ---- group reduction (within 16-lane group; lane0 tree stays clean) ----
    float vA = (jr < 10) ? accS : 0.f;
#pragma unroll
    for (int off = 1; off <= 8; off <<= 1) vA += __shfl_down(vA, off);
    if (jr == 0) P[q * 512 + d * 256 + b0 + c] = vA;
}

// ---------------------------------------------------------------------------
// Kernel 3: out[b] = sigmoid( sum over 16 segments x 2 directions )
// ---------------------------------------------------------------------------
__global__ __launch_bounds__(256) void final_kernel(const float* __restrict__ P,
                                                    float* __restrict__ out)
{
    const int b = threadIdx.x;
    float v = 0.f;
#pragma unroll
    for (int seg = 0; seg < 16; ++seg)
        v += P[seg * 512 + b] + P[seg * 512 + 256 + b];
    out[b] = frcp(1.f + fexp2(-v * L2E));
}

extern "C" void kernel_launch(void* const* d_in, const int* in_sizes, int n_in,
                              void* d_out, int out_size, void* d_ws, size_t ws_size,
                              hipStream_t stream)
{
    const float* x     = (const float*)d_in[0];
    const float* w4    = (const float*)d_in[1];
    const float* w5    = (const float*)d_in[2];
    const float* w6    = (const float*)d_in[3];
    const float* w7    = (const float*)d_in[4];
    const float* w8    = (const float*)d_in[5];
    const float* Wih_f = (const float*)d_in[6];
    const float* Whh_f = (const float*)d_in[7];
    const float* bih_f = (const float*)d_in[8];
    const float* bhh_f = (const float*)d_in[9];
    const float* Wih_r = (const float*)d_in[10];
    const float* Whh_r = (const float*)d_in[11];
    const float* bih_r = (const float*)d_in[12];
    const float* bhh_r = (const float*)d_in[13];

    // ws layout (fp32): lin [256][4096][16] (64MB) | P[8192] | MMu[1280] | Wp[1280]
    float*    lin = (float*)d_ws;
    float*    P   = lin + (size_t)NBATCH * SEQ * 16;
    unsigned* MMu = (unsigned*)(P + 8192);
    float*    Wpp = (float*)(MMu + 1280);

    wprep_kernel<<<1, 256, 0, stream>>>(Wih_f, bih_f, bhh_f,
                                        Wih_r, bih_r, bhh_r, Wpp, MMu);
    max_kernel<<<4 * NBATCH, 256, 0, stream>>>(x, w4, w5, w6, w7, w8, MMu);
    scatter_kernel<<<4 * NBATCH, 256, 0, stream>>>(x, w4, w5, w6, w7, w8, MMu, lin);
    lstm_kernel<<<2048, 64, 0, stream>>>(lin, Wpp, Whh_f, Whh_r, P);
    final_kernel<<<1, NBATCH, 0, stream>>>(P, (float*)d_out);
}

// Round 4
// 254.691 us; speedup vs baseline: 1.5820x; 1.0585x over previous
//
#include <hip/hip_runtime.h>

#define SEQ 4096
#define NBATCH 256

typedef float v2f __attribute__((ext_vector_type(2)));

__device__ __forceinline__ float sqf(float v) { return v * v; }
__device__ __forceinline__ float fexp2(float v) { return __builtin_amdgcn_exp2f(v); }
__device__ __forceinline__ float frcp(float v)  { return __builtin_amdgcn_rcpf(v); }

#define L2E 1.4426950408889634f

// order-preserving float<->uint key for atomicMax on floats
__device__ __forceinline__ unsigned fkey(float f) {
    const int b = __float_as_int(f);
    return (unsigned)(b ^ ((b >> 31) | 0x80000000));
}
__device__ __forceinline__ float fival(unsigned k) {
    const int b = (k & 0x80000000u) ? (int)(k ^ 0x80000000u) : (int)(~k);
    return __int_as_float(b);
}

// ---------------------------------------------------------------------------
// Kernel 0: fold the 24-wide input matvec into 12 inputs + bias, pre-scaled
// by the row's activation pre-scale (-log2e; -2log2e for g rows).
// NEW layout (r4): Wq[d][unit][k][gate] float4-quads {i,f,g,o} so each lstm
// lane loads its unit's 13 gate-quads once into VGPRs (no producer phase).
// Also zero-initializes the MMu atomic-max buffer (re-poisoned every call).
// ---------------------------------------------------------------------------
__global__ void wprep_kernel(
    const float* __restrict__ Wih_f, const float* __restrict__ bih_f,
    const float* __restrict__ bhh_f,
    const float* __restrict__ Wih_r, const float* __restrict__ bih_r,
    const float* __restrict__ bhh_r,
    float* __restrict__ Wq, unsigned* __restrict__ MMu)
{
    const int t = threadIdx.x;
    for (int i = t; i < NBATCH * 5; i += 256) MMu[i] = 0u;  // key 0 < any real
    if (t >= 80) return;
    const int d = t / 40, r = t % 40;
    const int gate = r / 10, unit = r % 10;
    const float* __restrict__ W  = (d ? Wih_r : Wih_f) + r * 24;
    const float* __restrict__ bi = d ? bih_r : bih_f;
    const float* __restrict__ bh = d ? bhh_r : bhh_f;
    const float sc = (gate == 2) ? (-2.f * L2E) : (-L2E);
    float o[13];
    o[0]  = W[0] + W[1] + W[2] + W[3];                // v4s
    o[1]  = W[4] + W[5] + W[6] + W[7];                // v5s
    o[2]  = W[4];                                     // v5p
    o[3]  = W[8] + W[9] + W[10] + W[11];              // v6s
    o[4]  = W[8] + W[9];                              // v6p
    o[5]  = W[12] + W[13] + W[14] + W[15];            // v7s
    o[6]  = W[12] + W[13] + W[14];                    // v7p
    o[7]  = W[16] + W[17] + W[18] + W[19];            // v8s+v8p
    o[8]  = W[20]; o[9] = W[21]; o[10] = W[22]; o[11] = W[23];   // x0..x3
    o[12] = bi[r] + bh[r];
#pragma unroll
    for (int k = 0; k < 13; ++k)
        Wq[(((d * 10) + unit) * 13 + k) * 4 + gate] = o[k] * sc;
}

// ---------------------------------------------------------------------------
// Kernel 1a: per-batch conv max -> atomicMax on uint keys.
// ---------------------------------------------------------------------------
__global__ __launch_bounds__(256) void max_kernel(
    const float* __restrict__ x,
    const float* __restrict__ w4p, const float* __restrict__ w5p,
    const float* __restrict__ w6p, const float* __restrict__ w7p,
    const float* __restrict__ w8p,
    unsigned* __restrict__ MMu)
{
    const int b    = blockIdx.x >> 2;
    const int quar = blockIdx.x & 3;
    const int tid  = threadIdx.x;
    const float* __restrict__ xr = x + (size_t)b * (4 * SEQ);

    float W4[4], W5[5], W6[6], W7[7], W8[8];
#pragma unroll
    for (int k = 0; k < 4; ++k) W4[k] = w4p[k];
#pragma unroll
    for (int k = 0; k < 5; ++k) W5[k] = w5p[k];
#pragma unroll
    for (int k = 0; k < 6; ++k) W6[k] = w6p[k];
#pragma unroll
    for (int k = 0; k < 7; ++k) W7[k] = w7p[k];
#pragma unroll
    for (int k = 0; k < 8; ++k) W8[k] = w8p[k];

    float m4 = -3.4e38f, m5 = -3.4e38f, m6 = -3.4e38f, m7 = -3.4e38f, m8 = -3.4e38f;
    for (int i = quar * (SEQ / 4) + tid; i < (quar + 1) * (SEQ / 4); i += 256) {
        const float4 t0 = *reinterpret_cast<const float4*>(xr + 4 * i);
        const float xa0 = t0.x, xa1 = t0.y, xa2 = t0.z, xa3 = t0.w;
        const float c4 = xa0 * W4[0] + xa1 * W4[1] + xa2 * W4[2] + xa3 * W4[3];
        m4 = fmaxf(m4, c4);
        if (i < SEQ - 1) {
            const float4 t1 = *reinterpret_cast<const float4*>(xr + 4 * i + 4);
            const float xa4 = t1.x, xa5 = t1.y, xa6 = t1.z, xa7 = t1.w;
            const float c5 = xa0*W5[0]+xa1*W5[1]+xa2*W5[2]+xa3*W5[3]+xa4*W5[4];
            const float c6 = xa0*W6[0]+xa1*W6[1]+xa2*W6[2]+xa3*W6[3]+xa4*W6[4]+xa5*W6[5];
            const float c7 = xa0*W7[0]+xa1*W7[1]+xa2*W7[2]+xa3*W7[3]+xa4*W7[4]+xa5*W7[5]+xa6*W7[6];
            const float c8 = xa0*W8[0]+xa1*W8[1]+xa2*W8[2]+xa3*W8[3]+xa4*W8[4]+xa5*W8[5]+xa6*W8[6]+xa7*W8[7];
            m5 = fmaxf(m5, c5); m6 = fmaxf(m6, c6);
            m7 = fmaxf(m7, c7); m8 = fmaxf(m8, c8);
        }
    }
#pragma unroll
    for (int off = 32; off; off >>= 1) {
        m4 = fmaxf(m4, __shfl_down(m4, off));
        m5 = fmaxf(m5, __shfl_down(m5, off));
        m6 = fmaxf(m6, __shfl_down(m6, off));
        m7 = fmaxf(m7, __shfl_down(m7, off));
        m8 = fmaxf(m8, __shfl_down(m8, off));
    }
    __shared__ float wr[4][5];
    if ((tid & 63) == 0) {
        const int w = tid >> 6;
        wr[w][0] = m4; wr[w][1] = m5; wr[w][2] = m6; wr[w][3] = m7; wr[w][4] = m8;
    }
    __syncthreads();
    if (tid < 5) {
        const float m = fmaxf(fmaxf(wr[0][tid], wr[1][tid]),
                              fmaxf(wr[2][tid], wr[3][tid]));
        atomicMax(&MMu[b * 5 + tid], fkey(m));
    }
}

// ---------------------------------------------------------------------------
// Kernel 1b: winner-takes-all -> compressed 12-input rows.
// lin[b][s][16] = {v4s, v5s, v5p, v6s, v6p, v7s, v7p, v8s+v8p,
//                  x0, x1, x2, x3, xsum, 0,0,0}
// ---------------------------------------------------------------------------
__global__ __launch_bounds__(256) void scatter_kernel(
    const float* __restrict__ x,
    const float* __restrict__ w4p, const float* __restrict__ w5p,
    const float* __restrict__ w6p, const float* __restrict__ w7p,
    const float* __restrict__ w8p,
    const unsigned* __restrict__ MMu,
    float* __restrict__ lin)
{
    const int b    = blockIdx.x >> 2;
    const int quar = blockIdx.x & 3;
    const int tid  = threadIdx.x;
    const float* __restrict__ xr = x + (size_t)b * (4 * SEQ);

    float W4[4], W5[5], W6[6], W7[7], W8[8];
#pragma unroll
    for (int k = 0; k < 4; ++k) W4[k] = w4p[k];
#pragma unroll
    for (int k = 0; k < 5; ++k) W5[k] = w5p[k];
#pragma unroll
    for (int k = 0; k < 6; ++k) W6[k] = w6p[k];
#pragma unroll
    for (int k = 0; k < 7; ++k) W7[k] = w7p[k];
#pragma unroll
    for (int k = 0; k < 8; ++k) W8[k] = w8p[k];

    const float M4 = fival(MMu[b * 5 + 0]), M5 = fival(MMu[b * 5 + 1]),
                M6 = fival(MMu[b * 5 + 2]), M7 = fival(MMu[b * 5 + 3]),
                M8 = fival(MMu[b * 5 + 4]);

    for (int s = quar * (SEQ / 4) + tid; s < (quar + 1) * (SEQ / 4); s += 256) {
        float xw[12];
        if (s > 0) {
            const float4 t = *reinterpret_cast<const float4*>(xr + 4 * s - 4);
            xw[0] = t.x; xw[1] = t.y; xw[2] = t.z; xw[3] = t.w;
        } else { xw[0] = xw[1] = xw[2] = xw[3] = 0.f; }
        {
            const float4 t = *reinterpret_cast<const float4*>(xr + 4 * s);
            xw[4] = t.x; xw[5] = t.y; xw[6] = t.z; xw[7] = t.w;
        }
        if (s < SEQ - 1) {
            const float4 t = *reinterpret_cast<const float4*>(xr + 4 * s + 4);
            xw[8] = t.x; xw[9] = t.y; xw[10] = t.z; xw[11] = t.w;
        } else { xw[8] = xw[9] = xw[10] = xw[11] = 0.f; }

        float c4s = 0.f, c5s = 0.f, c6s = 0.f, c7s = 0.f, c8s = 0.f;
        float c5p = 0.f, c6p = 0.f, c7p = 0.f, c8p = 0.f;
#pragma unroll
        for (int t = 0; t < 4; ++t) c4s += xw[4 + t] * W4[t];
#pragma unroll
        for (int t = 0; t < 5; ++t) { c5s += xw[4 + t] * W5[t]; c5p += xw[t] * W5[t]; }
#pragma unroll
        for (int t = 0; t < 6; ++t) { c6s += xw[4 + t] * W6[t]; c6p += xw[t] * W6[t]; }
#pragma unroll
        for (int t = 0; t < 7; ++t) { c7s += xw[4 + t] * W7[t]; c7p += xw[t] * W7[t]; }
#pragma unroll
        for (int t = 0; t < 8; ++t) { c8s += xw[4 + t] * W8[t]; c8p += xw[t] * W8[t]; }

        const bool oks = (s < SEQ - 1);
        const bool okp = (s > 0);
        const float v4s = sqf(c4s + M4);
        const float v5s = oks ? sqf(c5s + M5) : 0.f;
        const float v6s = oks ? sqf(c6s + M6) : 0.f;
        const float v7s = oks ? sqf(c7s + M7) : 0.f;
        const float v8s = oks ? sqf(c8s + M8) : 0.f;
        const float v5p = okp ? sqf(c5p + M5) : 0.f;
        const float v6p = okp ? sqf(c6p + M6) : 0.f;
        const float v7p = okp ? sqf(c7p + M7) : 0.f;
        const float v8p = okp ? sqf(c8p + M8) : 0.f;

        const float xsum = (xw[4] + xw[5]) + (xw[6] + xw[7]);
        float4* op = reinterpret_cast<float4*>(lin + ((size_t)b * SEQ + s) * 16);
        op[0] = make_float4(v4s, v5s, v5p, v6s);
        op[1] = make_float4(v6p, v7s, v7p, v8s + v8p);
        op[2] = make_float4(xw[4], xw[5], xw[6], xw[7]);
        op[3] = make_float4(xsum, 0.f, 0.f, 0.f);
    }
}

// ---------------------------------------------------------------------------
// Kernel 2 (r4): producer-less segmented bidirectional LSTM.
// r1/r3 post-mortems: per-chain-step cost invariant under ILP and TLP;
// only instruction removal (r2) moved it -> issue/mix-bound. So the
// producer phase is deleted: each consumer lane (c=chain, jr=unit) computes
// its own gate-quad input matvec with VGPR-resident weights (13 v2f pairs
// per i/f and g/o, loaded once from wprep's [d][unit][k][gate] layout).
// Raw lin rows are staged per 16-step chunk: 4 coalesced float4 loads +
// 4 ds_write_b128 into vbuf[k*256 + row*4] (single buffer; same-wave DS
// in-order makes chunk n's writes safely follow chunk n-1's reads).
// Consumer reads its row by group-broadcast ds_read (conflict-free).
// In-matvec is h-independent -> hides the h LDS round-trip latency.
// All float accumulation orders are BIT-IDENTICAL to r3 (even/odd v2f
// split, same fused activations) so absmax stays 0.
// Grid = 16 seg x 2 dir x 64 bgroups = 2048 x 64 thr, 2 waves/SIMD.
// nseg=16, own=256, warm=128; seg0 exact reset preserved.
// ---------------------------------------------------------------------------
__global__ __launch_bounds__(64, 2) void lstm_kernel(
    const float* __restrict__ lin,
    const float* __restrict__ Wq,
    const float* __restrict__ Whh_f,
    const float* __restrict__ Whh_r,
    float* __restrict__ P)
{
    const int bg   = blockIdx.x & 63;
    const int d    = (blockIdx.x >> 6) & 1;
    const int q    = blockIdx.x >> 7;          // 0..15 = segment
    const int b0   = bg * 4;
    const int lane = threadIdx.x;

    const int s0 = q * 256 - 128;              // negative for q=0 (clamped)
    const int nChunks = 24, warmChunks = 8;    // 16-step chunks, 384 steps

    __shared__ float vbuf[1024];               // [quad k][row][4]: k*256+row*4
    __shared__ float hb[64];                   // [chain][16] broadcast h

    // ---- consumer lane roles ----
    const int c   = lane >> 4;
    const int jr  = lane & 15;
    const int jc  = (jr < 10) ? jr : 0;

    hb[lane] = 0.f;

    // per-lane input-matvec weights: 13 gate-quads {i,f,g,o} for unit jc
    v2f wINif[13], wINgo[13];
    {
        const float4* __restrict__ Wqp =
            reinterpret_cast<const float4*>(Wq) + (d * 10 + jc) * 13;
#pragma unroll
        for (int k = 0; k < 13; ++k) {
            const float4 w = Wqp[k];
            wINif[k] = (v2f){w.x, w.y};
            wINgo[k] = (v2f){w.z, w.w};
        }
    }
    // recurrent weights (pre-scaled)
    const float* __restrict__ Whh = d ? Whh_r : Whh_f;
    v2f wIF[10], wGO[10];
#pragma unroll
    for (int k = 0; k < 10; ++k) {
        wIF[k] = (v2f){Whh[jc * 10 + k]        * (-L2E),
                       Whh[(10 + jc) * 10 + k] * (-L2E)};
        wGO[k] = (v2f){Whh[(20 + jc) * 10 + k] * (-2.f * L2E),
                       Whh[(30 + jc) * 10 + k] * (-L2E)};
    }

    // ---- staging role: lane stages row (step lane>>2, chain lane&3) ----
    const int lc = lane & 3;
    const int lr = lane >> 2;                  // 0..15
    const float* __restrict__ chbase = lin + (size_t)(b0 + lc) * SEQ * 16;

    auto srcp = [&](int cn) {
        int sp = s0 + cn * 16 + lr;
        if (sp < 0) sp = 0;                    // q=0 warm region: clamped garbage,
                                               // discarded by the state reset
        const int pos = d ? (SEQ - 1 - sp) : sp;
        return reinterpret_cast<const float4*>(chbase + (size_t)pos * 16);
    };

    float4 pR0, pR1, pR2, pR3;
    {
        const float4* a = srcp(0);
        pR0 = a[0]; pR1 = a[1]; pR2 = a[2]; pR3 = a[3];
    }

    float cs = 0.f, accS = 0.f;

    // one recurrence step; h round-trips through hb (same-wave DS in-order)
    auto step = [&](int i) {
        const int ro = (i * 4 + c) * 4;        // float offset of this row
        const float4 q0 = *reinterpret_cast<const float4*>(&vbuf[ro]);
        const float4 q1 = *reinterpret_cast<const float4*>(&vbuf[256 + ro]);
        const float4 q2 = *reinterpret_cast<const float4*>(&vbuf[512 + ro]);
        const float  sx = vbuf[768 + ro];      // xsum = float 12 of the row
        const float vv[12] = {q0.x, q0.y, q0.z, q0.w,
                              q1.x, q1.y, q1.z, q1.w,
                              q2.x, q2.y, q2.z, q2.w};
        // in-matvec (bit-identical order to r3's producer: even/odd split)
        v2f eI0 = wINif[12], eI1 = (v2f){0.f, 0.f};
        v2f eG0 = wINgo[12], eG1 = (v2f){0.f, 0.f};
#pragma unroll
        for (int k = 0; k < 12; k += 2) {
            const v2f v0 = (v2f){vv[k], vv[k]};
            const v2f v1 = (v2f){vv[k + 1], vv[k + 1]};
            eI0 += v0 * wINif[k]; eI1 += v1 * wINif[k + 1];
            eG0 += v0 * wINgo[k]; eG1 += v1 * wINgo[k + 1];
        }
        const v2f sIF = eI0 + eI1;             // {i,f} input part (== r3 gp4.xy)
        const v2f sGO = eG0 + eG1;             // {g,o} input part (== r3 gp4.zw)
        // h-matvec (same structure as r3 consumer)
        const float4 h03 = *reinterpret_cast<const float4*>(&hb[c * 16 + 0]);
        const float4 h47 = *reinterpret_cast<const float4*>(&hb[c * 16 + 4]);
        const float2 h89 = *reinterpret_cast<const float2*>(&hb[c * 16 + 8]);
        const float hj[10] = {h03.x, h03.y, h03.z, h03.w,
                              h47.x, h47.y, h47.z, h47.w, h89.x, h89.y};
        v2f eif0 = sIF, eif1 = (v2f){0.f, 0.f};
        v2f ego0 = sGO, ego1 = (v2f){0.f, 0.f};
#pragma unroll
        for (int k = 0; k < 10; k += 2) {
            const v2f h0 = (v2f){hj[k], hj[k]};
            const v2f h1 = (v2f){hj[k + 1], hj[k + 1]};
            eif0 += h0 * wIF[k]; eif1 += h1 * wIF[k + 1];
            ego0 += h0 * wGO[k]; ego1 += h1 * wGO[k + 1];
        }
        const v2f eif = eif0 + eif1, ego = ego0 + ego1;
        // eif.x=-l2e*i  eif.y=-l2e*f  ego.x=-2l2e*g  ego.y=-l2e*o
        const float Ai = fexp2(eif.x);                 // e^-i
        const float Fv = fexp2(eif.y);                 // e^-f
        const float Bg = fexp2(fminf(ego.x, 80.f));    // e^-2g (clamped: no inf*0)
        const float Ov = fexp2(ego.y);                 // e^-o
        const float sf = frcp(1.f + Fv);
        // -2l2e * sigmoid(i)*tanh(g) = (2l2e*Bg - 2l2e) / ((1+Ai)(1+Bg))
        const float it = fmaf(Bg, 2.f * L2E, -2.f * L2E) *
                         frcp((1.f + Ai) * (1.f + Bg));
        cs = fmaf(sf, cs, it);                         // cs = -2l2e * c
        const float Dv = fexp2(fminf(cs, 80.f));       // e^-2c (clamped)
        // sigmoid(o)*tanh(c) = (1-Dv) / ((1+Ov)(1+Dv))
        const float hv = (1.f - Dv) * frcp((1.f + Ov) * (1.f + Dv));
        hb[c * 16 + jr] = hv;                          // jr>=10 -> harmless pad
        accS = fmaf(sx, hv, accS);
    };

    for (int cn = 0; cn < nChunks; ++cn) {
        // ---- stage current chunk (regs -> LDS); row == lane ----
        *reinterpret_cast<float4*>(&vbuf[lane * 4])       = pR0;
        *reinterpret_cast<float4*>(&vbuf[256 + lane * 4]) = pR1;
        *reinterpret_cast<float4*>(&vbuf[512 + lane * 4]) = pR2;
        *reinterpret_cast<float4*>(&vbuf[768 + lane * 4]) = pR3;
        asm volatile("s_waitcnt lgkmcnt(0)" ::: "memory");
        // ---- issue next chunk's loads (overlap the 16-step consume) ----
        {
            const int nc = (cn + 1 < nChunks) ? cn + 1 : cn;
            const float4* a = srcp(nc);
            pR0 = a[0]; pR1 = a[1]; pR2 = a[2]; pR3 = a[3];
        }
        // ---- consume 16 steps (serial chain; in-matvec fills stalls) ----
#pragma unroll 4
        for (int i = 0; i < 16; ++i) step(i);
        if (cn + 1 == warmChunks) {
            accS = 0.f;                        // drop warmup contributions
            if (q == 0) {                      // seg0: exact zero init at s=0
                cs = 0.f;
                hb[lane] = 0.f;
            }
        }
    }

    // ---- group reduction (within 16-lane group; lane0 tree stays clean) ----
    float vA = (jr < 10) ? accS : 0.f;
#pragma unroll
    for (int off = 1; off <= 8; off <<= 1) vA += __shfl_down(vA, off);
    if (jr == 0) P[q * 512 + d * 256 + b0 + c] = vA;
}

// ---------------------------------------------------------------------------
// Kernel 3: out[b] = sigmoid( sum over 16 segments x 2 directions )
// ---------------------------------------------------------------------------
__global__ __launch_bounds__(256) void final_kernel(const float* __restrict__ P,
                                                    float* __restrict__ out)
{
    const int b = threadIdx.x;
    float v = 0.f;
#pragma unroll
    for (int seg = 0; seg < 16; ++seg)
        v += P[seg * 512 + b] + P[seg * 512 + 256 + b];
    out[b] = frcp(1.f + fexp2(-v * L2E));
}

extern "C" void kernel_launch(void* const* d_in, const int* in_sizes, int n_in,
                              void* d_out, int out_size, void* d_ws, size_t ws_size,
                              hipStream_t stream)
{
    const float* x     = (const float*)d_in[0];
    const float* w4    = (const float*)d_in[1];
    const float* w5    = (const float*)d_in[2];
    const float* w6    = (const float*)d_in[3];
    const float* w7    = (const float*)d_in[4];
    const float* w8    = (const float*)d_in[5];
    const float* Wih_f = (const float*)d_in[6];
    const float* Whh_f = (const float*)d_in[7];
    const float* bih_f = (const float*)d_in[8];
    const float* bhh_f = (const float*)d_in[9];
    const float* Wih_r = (const float*)d_in[10];
    const float* Whh_r = (const float*)d_in[11];
    const float* bih_r = (const float*)d_in[12];
    const float* bhh_r = (const float*)d_in[13];

    // ws layout (fp32): lin [256][4096][16] (64MB) | P[8192] | MMu[1280] | Wq[1280]
    float*    lin = (float*)d_ws;
    float*    P   = lin + (size_t)NBATCH * SEQ * 16;
    unsigned* MMu = (unsigned*)(P + 8192);
    float*    Wqp = (float*)(MMu + 1280);

    wprep_kernel<<<1, 256, 0, stream>>>(Wih_f, bih_f, bhh_f,
                                        Wih_r, bih_r, bhh_r, Wqp, MMu);
    max_kernel<<<4 * NBATCH, 256, 0, stream>>>(x, w4, w5, w6, w7, w8, MMu);
    scatter_kernel<<<4 * NBATCH, 256, 0, stream>>>(x, w4, w5, w6, w7, w8, MMu, lin);
    lstm_kernel<<<2048, 64, 0, stream>>>(lin, Wqp, Whh_f, Whh_r, P);
    final_kernel<<<1, NBATCH, 0, stream>>>(P, (float*)d_out);
}

// Round 5
// 244.773 us; speedup vs baseline: 1.6462x; 1.0405x over previous
//
#include <hip/hip_runtime.h>

#define SEQ 4096
#define NBATCH 256

__device__ __forceinline__ float sqf(float v) { return v * v; }
__device__ __forceinline__ float fexp2(float v) { return __builtin_amdgcn_exp2f(v); }
__device__ __forceinline__ float frcp(float v)  { return __builtin_amdgcn_rcpf(v); }

#define L2E 1.4426950408889634f

// order-preserving float<->uint key for atomicMax on floats
__device__ __forceinline__ unsigned fkey(float f) {
    const int b = __float_as_int(f);
    return (unsigned)(b ^ ((b >> 31) | 0x80000000));
}
__device__ __forceinline__ float fival(unsigned k) {
    const int b = (k & 0x80000000u) ? (int)(k ^ 0x80000000u) : (int)(~k);
    return __int_as_float(b);
}

// ---------------------------------------------------------------------------
// Kernel 1a: per-batch conv max -> atomicMax on uint keys.
// (MMu is zeroed by hipMemsetAsync before this kernel.)
// ---------------------------------------------------------------------------
__global__ __launch_bounds__(256) void max_kernel(
    const float* __restrict__ x,
    const float* __restrict__ w4p, const float* __restrict__ w5p,
    const float* __restrict__ w6p, const float* __restrict__ w7p,
    const float* __restrict__ w8p,
    unsigned* __restrict__ MMu)
{
    const int b    = blockIdx.x >> 2;
    const int quar = blockIdx.x & 3;
    const int tid  = threadIdx.x;
    const float* __restrict__ xr = x + (size_t)b * (4 * SEQ);

    float W4[4], W5[5], W6[6], W7[7], W8[8];
#pragma unroll
    for (int k = 0; k < 4; ++k) W4[k] = w4p[k];
#pragma unroll
    for (int k = 0; k < 5; ++k) W5[k] = w5p[k];
#pragma unroll
    for (int k = 0; k < 6; ++k) W6[k] = w6p[k];
#pragma unroll
    for (int k = 0; k < 7; ++k) W7[k] = w7p[k];
#pragma unroll
    for (int k = 0; k < 8; ++k) W8[k] = w8p[k];

    float m4 = -3.4e38f, m5 = -3.4e38f, m6 = -3.4e38f, m7 = -3.4e38f, m8 = -3.4e38f;
    for (int i = quar * (SEQ / 4) + tid; i < (quar + 1) * (SEQ / 4); i += 256) {
        const float4 t0 = *reinterpret_cast<const float4*>(xr + 4 * i);
        const float xa0 = t0.x, xa1 = t0.y, xa2 = t0.z, xa3 = t0.w;
        const float c4 = xa0 * W4[0] + xa1 * W4[1] + xa2 * W4[2] + xa3 * W4[3];
        m4 = fmaxf(m4, c4);
        if (i < SEQ - 1) {
            const float4 t1 = *reinterpret_cast<const float4*>(xr + 4 * i + 4);
            const float xa4 = t1.x, xa5 = t1.y, xa6 = t1.z, xa7 = t1.w;
            const float c5 = xa0*W5[0]+xa1*W5[1]+xa2*W5[2]+xa3*W5[3]+xa4*W5[4];
            const float c6 = xa0*W6[0]+xa1*W6[1]+xa2*W6[2]+xa3*W6[3]+xa4*W6[4]+xa5*W6[5];
            const float c7 = xa0*W7[0]+xa1*W7[1]+xa2*W7[2]+xa3*W7[3]+xa4*W7[4]+xa5*W7[5]+xa6*W7[6];
            const float c8 = xa0*W8[0]+xa1*W8[1]+xa2*W8[2]+xa3*W8[3]+xa4*W8[4]+xa5*W8[5]+xa6*W8[6]+xa7*W8[7];
            m5 = fmaxf(m5, c5); m6 = fmaxf(m6, c6);
            m7 = fmaxf(m7, c7); m8 = fmaxf(m8, c8);
        }
    }
#pragma unroll
    for (int off = 32; off; off >>= 1) {
        m4 = fmaxf(m4, __shfl_down(m4, off));
        m5 = fmaxf(m5, __shfl_down(m5, off));
        m6 = fmaxf(m6, __shfl_down(m6, off));
        m7 = fmaxf(m7, __shfl_down(m7, off));
        m8 = fmaxf(m8, __shfl_down(m8, off));
    }
    __shared__ float wr[4][5];
    if ((tid & 63) == 0) {
        const int w = tid >> 6;
        wr[w][0] = m4; wr[w][1] = m5; wr[w][2] = m6; wr[w][3] = m7; wr[w][4] = m8;
    }
    __syncthreads();
    if (tid < 5) {
        const float m = fmaxf(fmaxf(wr[0][tid], wr[1][tid]),
                              fmaxf(wr[2][tid], wr[3][tid]));
        atomicMax(&MMu[b * 5 + tid], fkey(m));
    }
}

// ---------------------------------------------------------------------------
// Kernel 2 (r5): fully fused segmented bidirectional LSTM.
// r4 post-mortem: VGPR=76 < the 92 weights need -> compiler rematerialized
// the (plain-load) weight arrays inside the hot loop. Fixes this round:
//  (a) weights are FOLDED ARITHMETICALLY in-kernel (computed values, not
//      rematable loads), pinned with asm "+v", and amdgpu_waves_per_eu(2,2)
//      gives the allocator the full 256-VGPR / 2-wave budget.
//  (b) step math scalarized (no v2f splat-building), same accumulation
//      order per gate (even/odd split preserved).
//  (c) scatter_kernel + wprep_kernel + lin buffer DELETED: staging lanes
//      recompute the conv rows on the fly from x (bit-identical expression
//      order to the old scatter), MMu init via hipMemsetAsync.
// Structure: grid = 16 seg x 2 dir x 64 bgroups = 2048 x 64 thr,
// 2 waves/SIMD; 4 chains/wave; nseg=16, own=256, warm=128; seg0 exact
// reset preserved; h state broadcast through hb[] in LDS.
// ---------------------------------------------------------------------------
__global__ __launch_bounds__(64) __attribute__((amdgpu_waves_per_eu(2, 2)))
void lstm_kernel(
    const float* __restrict__ x,
    const float* __restrict__ w4p, const float* __restrict__ w5p,
    const float* __restrict__ w6p, const float* __restrict__ w7p,
    const float* __restrict__ w8p,
    const unsigned* __restrict__ MMu,
    const float* __restrict__ Wih_f, const float* __restrict__ bih_f,
    const float* __restrict__ bhh_f,
    const float* __restrict__ Wih_r, const float* __restrict__ bih_r,
    const float* __restrict__ bhh_r,
    const float* __restrict__ Whh_f, const float* __restrict__ Whh_r,
    float* __restrict__ P)
{
    const int bg   = blockIdx.x & 63;
    const int d    = (blockIdx.x >> 6) & 1;
    const int q    = blockIdx.x >> 7;          // 0..15 = segment
    const int b0   = bg * 4;
    const int lane = threadIdx.x;

    const int s0 = q * 256 - 128;              // negative for q=0 (clamped)
    const int nChunks = 24, warmChunks = 8;    // 16-step chunks, 384 steps

    __shared__ float vbuf[1024];               // [quad k][row][4]: k*256+row*4
    __shared__ float hb[64];                   // [chain][16] broadcast h

    const int c  = lane >> 4;
    const int jr = lane & 15;
    const int jc = (jr < 10) ? jr : 0;

    hb[lane] = 0.f;

    // ---- fold input weights (old wprep math) for (dir d, unit jc) ----
    const float* __restrict__ Wih = d ? Wih_r : Wih_f;
    const float* __restrict__ bi  = d ? bih_r : bih_f;
    const float* __restrict__ bh  = d ? bhh_r : bhh_f;
    float wI[13], wF[13], wG[13], wO[13];
    auto fold = [&](int g, float sc, float* w) {
        const int r = g * 10 + jc;
        const float* __restrict__ W = Wih + r * 24;
        w[0]  = (W[0] + W[1] + W[2] + W[3]) * sc;                // v4s
        w[1]  = (W[4] + W[5] + W[6] + W[7]) * sc;                // v5s
        w[2]  = W[4] * sc;                                       // v5p
        w[3]  = (W[8] + W[9] + W[10] + W[11]) * sc;              // v6s
        w[4]  = (W[8] + W[9]) * sc;                              // v6p
        w[5]  = (W[12] + W[13] + W[14] + W[15]) * sc;            // v7s
        w[6]  = (W[12] + W[13] + W[14]) * sc;                    // v7p
        w[7]  = (W[16] + W[17] + W[18] + W[19]) * sc;            // v8s+v8p
        w[8]  = W[20] * sc; w[9] = W[21] * sc;
        w[10] = W[22] * sc; w[11] = W[23] * sc;                  // x0..x3
        w[12] = (bi[r] + bh[r]) * sc;                            // bias
    };
    fold(0, -L2E, wI); fold(1, -L2E, wF);
    fold(2, -2.f * L2E, wG); fold(3, -L2E, wO);

    // recurrent weights (pre-scaled)
    const float* __restrict__ Whh = d ? Whh_r : Whh_f;
    float hI[10], hF[10], hG[10], hO[10];
#pragma unroll
    for (int k = 0; k < 10; ++k) {
        hI[k] = Whh[jc * 10 + k]        * (-L2E);
        hF[k] = Whh[(10 + jc) * 10 + k] * (-L2E);
        hG[k] = Whh[(20 + jc) * 10 + k] * (-2.f * L2E);
        hO[k] = Whh[(30 + jc) * 10 + k] * (-L2E);
    }
    // pin all weights against rematerialization / re-load
#pragma unroll
    for (int k = 0; k < 13; ++k)
        asm volatile("" : "+v"(wI[k]), "+v"(wF[k]), "+v"(wG[k]), "+v"(wO[k]));
#pragma unroll
    for (int k = 0; k < 10; ++k)
        asm volatile("" : "+v"(hI[k]), "+v"(hF[k]), "+v"(hG[k]), "+v"(hO[k]));

    // ---- staging role: lane stages row (step lane>>2, chain lane&3) ----
    const int lc = lane & 3;
    const int lr = lane >> 2;                  // 0..15
    const float* __restrict__ xr = x + (size_t)(b0 + lc) * (4 * SEQ);

    float W4[4], W5[5], W6[6], W7[7], W8[8];
#pragma unroll
    for (int k = 0; k < 4; ++k) W4[k] = w4p[k];
#pragma unroll
    for (int k = 0; k < 5; ++k) W5[k] = w5p[k];
#pragma unroll
    for (int k = 0; k < 6; ++k) W6[k] = w6p[k];
#pragma unroll
    for (int k = 0; k < 7; ++k) W7[k] = w7p[k];
#pragma unroll
    for (int k = 0; k < 8; ++k) W8[k] = w8p[k];

    const float M4 = fival(MMu[(b0 + lc) * 5 + 0]);
    const float M5 = fival(MMu[(b0 + lc) * 5 + 1]);
    const float M6 = fival(MMu[(b0 + lc) * 5 + 2]);
    const float M7 = fival(MMu[(b0 + lc) * 5 + 3]);
    const float M8 = fival(MMu[(b0 + lc) * 5 + 4]);

    auto posof = [&](int cn) {
        int sp = s0 + cn * 16 + lr;
        if (sp < 0) sp = 0;                    // q=0 warm region: clamped garbage,
                                               // discarded by the state reset
        return d ? (SEQ - 1 - sp) : sp;
    };
    auto loadx = [&](int pos, float4& A, float4& B, float4& C) {
        B = *reinterpret_cast<const float4*>(xr + 4 * pos);
        A = (pos > 0) ? *reinterpret_cast<const float4*>(xr + 4 * pos - 4)
                      : make_float4(0.f, 0.f, 0.f, 0.f);
        C = (pos < SEQ - 1) ? *reinterpret_cast<const float4*>(xr + 4 * pos + 4)
                            : make_float4(0.f, 0.f, 0.f, 0.f);
    };

    int posCur = posof(0);
    float4 xA, xB, xC;
    loadx(posCur, xA, xB, xC);

    float cs = 0.f, accS = 0.f;

    // one recurrence step; h round-trips through hb (same-wave DS in-order)
    auto step = [&](int i) {
        const int ro = (i * 4 + c) * 4;
        const float4 q0 = *reinterpret_cast<const float4*>(&vbuf[ro]);
        const float4 q1 = *reinterpret_cast<const float4*>(&vbuf[256 + ro]);
        const float4 q2 = *reinterpret_cast<const float4*>(&vbuf[512 + ro]);
        const float  sx = vbuf[768 + ro];
        const float vv[12] = {q0.x, q0.y, q0.z, q0.w,
                              q1.x, q1.y, q1.z, q1.w,
                              q2.x, q2.y, q2.z, q2.w};
        const float4 h03 = *reinterpret_cast<const float4*>(&hb[c * 16 + 0]);
        const float4 h47 = *reinterpret_cast<const float4*>(&hb[c * 16 + 4]);
        const float2 h89 = *reinterpret_cast<const float2*>(&hb[c * 16 + 8]);
        const float hj[10] = {h03.x, h03.y, h03.z, h03.w,
                              h47.x, h47.y, h47.z, h47.w, h89.x, h89.y};
        // in-matvec (same even/odd accumulation order as r3/r4)
        float ei0 = wI[12], ei1 = 0.f, ef0 = wF[12], ef1 = 0.f;
        float eg0 = wG[12], eg1 = 0.f, eo0 = wO[12], eo1 = 0.f;
#pragma unroll
        for (int k = 0; k < 12; k += 2) {
            ei0 = fmaf(vv[k], wI[k], ei0); ei1 = fmaf(vv[k + 1], wI[k + 1], ei1);
            ef0 = fmaf(vv[k], wF[k], ef0); ef1 = fmaf(vv[k + 1], wF[k + 1], ef1);
            eg0 = fmaf(vv[k], wG[k], eg0); eg1 = fmaf(vv[k + 1], wG[k + 1], eg1);
            eo0 = fmaf(vv[k], wO[k], eo0); eo1 = fmaf(vv[k + 1], wO[k + 1], eo1);
        }
        const float si = ei0 + ei1, sf2 = ef0 + ef1;
        const float sg = eg0 + eg1, so2 = eo0 + eo1;
        // h-matvec (same even/odd order)
        float ai0 = si, ai1 = 0.f, af0 = sf2, af1 = 0.f;
        float ag0 = sg, ag1 = 0.f, ao0 = so2, ao1 = 0.f;
#pragma unroll
        for (int k = 0; k < 10; k += 2) {
            ai0 = fmaf(hj[k], hI[k], ai0); ai1 = fmaf(hj[k + 1], hI[k + 1], ai1);
            af0 = fmaf(hj[k], hF[k], af0); af1 = fmaf(hj[k + 1], hF[k + 1], af1);
            ag0 = fmaf(hj[k], hG[k], ag0); ag1 = fmaf(hj[k + 1], hG[k + 1], ag1);
            ao0 = fmaf(hj[k], hO[k], ao0); ao1 = fmaf(hj[k + 1], hO[k + 1], ao1);
        }
        const float eI = ai0 + ai1, eF = af0 + af1;
        const float eG = ag0 + ag1, eO = ao0 + ao1;
        // eI=-l2e*i  eF=-l2e*f  eG=-2l2e*g  eO=-l2e*o
        const float Ai = fexp2(eI);                    // e^-i
        const float Fv = fexp2(eF);                    // e^-f
        const float Bg = fexp2(fminf(eG, 80.f));       // e^-2g (clamped: no inf*0)
        const float Ov = fexp2(eO);                    // e^-o
        const float sf = frcp(1.f + Fv);
        // -2l2e * sigmoid(i)*tanh(g) = (2l2e*Bg - 2l2e) / ((1+Ai)(1+Bg))
        const float it = fmaf(Bg, 2.f * L2E, -2.f * L2E) *
                         frcp((1.f + Ai) * (1.f + Bg));
        cs = fmaf(sf, cs, it);                         // cs = -2l2e * c
        const float Dv = fexp2(fminf(cs, 80.f));       // e^-2c (clamped)
        // sigmoid(o)*tanh(c) = (1-Dv) / ((1+Ov)(1+Dv))
        const float hv = (1.f - Dv) * frcp((1.f + Ov) * (1.f + Dv));
        hb[c * 16 + jr] = hv;                          // jr>=10 -> harmless pad
        accS = fmaf(sx, hv, accS);
    };

    for (int cn = 0; cn < nChunks; ++cn) {
        // ---- conv for this chunk's row (old scatter math, exact order) ----
        {
            const bool okp = posCur > 0, oks = posCur < SEQ - 1;
            float xw[12];
            xw[0] = xA.x; xw[1] = xA.y; xw[2]  = xA.z; xw[3]  = xA.w;
            xw[4] = xB.x; xw[5] = xB.y; xw[6]  = xB.z; xw[7]  = xB.w;
            xw[8] = xC.x; xw[9] = xC.y; xw[10] = xC.z; xw[11] = xC.w;

            float c4s = 0.f, c5s = 0.f, c6s = 0.f, c7s = 0.f, c8s = 0.f;
            float c5p = 0.f, c6p = 0.f, c7p = 0.f, c8p = 0.f;
#pragma unroll
            for (int t = 0; t < 4; ++t) c4s += xw[4 + t] * W4[t];
#pragma unroll
            for (int t = 0; t < 5; ++t) { c5s += xw[4 + t] * W5[t]; c5p += xw[t] * W5[t]; }
#pragma unroll
            for (int t = 0; t < 6; ++t) { c6s += xw[4 + t] * W6[t]; c6p += xw[t] * W6[t]; }
#pragma unroll
            for (int t = 0; t < 7; ++t) { c7s += xw[4 + t] * W7[t]; c7p += xw[t] * W7[t]; }
#pragma unroll
            for (int t = 0; t < 8; ++t) { c8s += xw[4 + t] * W8[t]; c8p += xw[t] * W8[t]; }

            const float v4s = sqf(c4s + M4);
            const float v5s = oks ? sqf(c5s + M5) : 0.f;
            const float v6s = oks ? sqf(c6s + M6) : 0.f;
            const float v7s = oks ? sqf(c7s + M7) : 0.f;
            const float v8s = oks ? sqf(c8s + M8) : 0.f;
            const float v5p = okp ? sqf(c5p + M5) : 0.f;
            const float v6p = okp ? sqf(c6p + M6) : 0.f;
            const float v7p = okp ? sqf(c7p + M7) : 0.f;
            const float v8p = okp ? sqf(c8p + M8) : 0.f;
            const float xsum = (xw[4] + xw[5]) + (xw[6] + xw[7]);

            *reinterpret_cast<float4*>(&vbuf[lane * 4]) =
                make_float4(v4s, v5s, v5p, v6s);
            *reinterpret_cast<float4*>(&vbuf[256 + lane * 4]) =
                make_float4(v6p, v7s, v7p, v8s + v8p);
            *reinterpret_cast<float4*>(&vbuf[512 + lane * 4]) =
                make_float4(xw[4], xw[5], xw[6], xw[7]);
            vbuf[768 + lane * 4] = xsum;
        }
        // ---- same-wave DS ordering (single wave: no barrier) ----
        asm volatile("s_waitcnt lgkmcnt(0)" ::: "memory");
        // ---- issue next chunk's x loads (overlap the 16-step consume) ----
        {
            const int nc = (cn + 1 < nChunks) ? cn + 1 : cn;
            posCur = posof(nc);
            loadx(posCur, xA, xB, xC);
        }
        // ---- consume 16 steps (serial chain; TLP + in-matvec hide latency) ----
#pragma unroll 4
        for (int i = 0; i < 16; ++i) step(i);
        if (cn + 1 == warmChunks) {
            accS = 0.f;                        // drop warmup contributions
            if (q == 0) {                      // seg0: exact zero init at s=0
                cs = 0.f;
                hb[lane] = 0.f;
            }
        }
    }

    // ---- group reduction (within 16-lane group; lane0 tree stays clean) ----
    float vA = (jr < 10) ? accS : 0.f;
#pragma unroll
    for (int off = 1; off <= 8; off <<= 1) vA += __shfl_down(vA, off);
    if (jr == 0) P[q * 512 + d * 256 + b0 + c] = vA;
}

// ---------------------------------------------------------------------------
// Kernel 3: out[b] = sigmoid( sum over 16 segments x 2 directions )
// ---------------------------------------------------------------------------
__global__ __launch_bounds__(256) void final_kernel(const float* __restrict__ P,
                                                    float* __restrict__ out)
{
    const int b = threadIdx.x;
    float v = 0.f;
#pragma unroll
    for (int seg = 0; seg < 16; ++seg)
        v += P[seg * 512 + b] + P[seg * 512 + 256 + b];
    out[b] = frcp(1.f + fexp2(-v * L2E));
}

extern "C" void kernel_launch(void* const* d_in, const int* in_sizes, int n_in,
                              void* d_out, int out_size, void* d_ws, size_t ws_size,
                              hipStream_t stream)
{
    const float* x     = (const float*)d_in[0];
    const float* w4    = (const float*)d_in[1];
    const float* w5    = (const float*)d_in[2];
    const float* w6    = (const float*)d_in[3];
    const float* w7    = (const float*)d_in[4];
    const float* w8    = (const float*)d_in[5];
    const float* Wih_f = (const float*)d_in[6];
    const float* Whh_f = (const float*)d_in[7];
    const float* bih_f = (const float*)d_in[8];
    const float* bhh_f = (const float*)d_in[9];
    const float* Wih_r = (const float*)d_in[10];
    const float* Whh_r = (const float*)d_in[11];
    const float* bih_r = (const float*)d_in[12];
    const float* bhh_r = (const float*)d_in[13];

    // ws layout (fp32): P[8192] | MMu[1280]   (lin + Wq buffers deleted)
    float*    P   = (float*)d_ws;
    unsigned* MMu = (unsigned*)(P + 8192);

    hipMemsetAsync(MMu, 0, 1280 * sizeof(unsigned), stream);
    max_kernel<<<4 * NBATCH, 256, 0, stream>>>(x, w4, w5, w6, w7, w8, MMu);
    lstm_kernel<<<2048, 64, 0, stream>>>(x, w4, w5, w6, w7, w8, MMu,
                                         Wih_f, bih_f, bhh_f,
                                         Wih_r, bih_r, bhh_r,
                                         Whh_f, Whh_r, P);
    final_kernel<<<1, NBATCH, 0, stream>>>(P, (float*)d_out);
}